// Round 14
// baseline (69.180 us; speedup 1.0000x reference)
//
#include <hip/hip_runtime.h>
#include <cmath>

#define D_ 128
#define B_ 256
#define P_ 64
#define R_ 32
#define GROWS 192        /* rel rows per batch block */
#define EPS_ 1e-8f

typedef unsigned short u16;
typedef unsigned int   u32;
using bf16x8 = __attribute__((ext_vector_type(8))) __bf16;
using f32x4  = __attribute__((ext_vector_type(4))) float;

__device__ __forceinline__ float sigm_f(float x){ return 1.0f/(1.0f + __expf(-x)); }
__device__ __forceinline__ float tanh_f(float x){
    float e = __expf(2.0f*x);
    return 1.0f - 2.0f/(e + 1.0f);
}

__device__ __forceinline__ u16 f2b(float f){         // fp32 -> bf16 RNE
    u32 u = __builtin_bit_cast(u32, f);
    u += 0x7fffu + ((u >> 16) & 1u);
    return (u16)(u >> 16);
}
__device__ __forceinline__ float b2f(u16 s){
    return __builtin_bit_cast(float, ((u32)s) << 16);
}
__device__ __forceinline__ bf16x8 pack8(float a0,float a1,float a2,float a3,
                                        float a4,float a5,float a6,float a7){
    uint4 r;
    r.x = (u32)f2b(a0) | ((u32)f2b(a1) << 16);
    r.y = (u32)f2b(a2) | ((u32)f2b(a3) << 16);
    r.z = (u32)f2b(a4) | ((u32)f2b(a5) << 16);
    r.w = (u32)f2b(a6) | ((u32)f2b(a7) << 16);
    return __builtin_bit_cast(bf16x8, r);
}
__device__ __forceinline__ bf16x8 ldg8(const u16* p){
    return __builtin_bit_cast(bf16x8, *(const uint4*)p);
}
// swizzled LDS bf16 tile: slot(row, granule g) at row*128 + ((g^(row&7))<<3)
__device__ __forceinline__ bf16x8 ldA(const u16* Xs, int row, int gk){
    return __builtin_bit_cast(bf16x8,
        *(const uint4*)(&Xs[row*128 + ((gk ^ (row & 7)) << 3)]));
}
__device__ __forceinline__ int swz_slot(int row, int col){
    return row*128 + (((col >> 3) ^ (row & 7)) << 3) + (col & 7);
}

// ---------------- K1: weight convert fp32 -> bf16 ----------------
__global__ __launch_bounds__(1024) void k_wcvt(
    const float* __restrict__ wd, const float* __restrict__ we,
    const float* __restrict__ wp, const float* __restrict__ wih,
    const float* __restrict__ whh,
    u16* __restrict__ wdb, u16* __restrict__ web, u16* __restrict__ wpb,
    u16* __restrict__ wib, u16* __restrict__ whb)
{
    int i = blockIdx.x*1024 + threadIdx.x;    // 0..18431
    int e = i*8;
    const float* src; u16* dst; int off;
    if      (e < 16384) { src = wd;  dst = wdb; off = e; }
    else if (e < 32768) { src = we;  dst = web; off = e - 16384; }
    else if (e < 49152) { src = wp;  dst = wpb; off = e - 32768; }
    else if (e < 98304) { src = wih; dst = wib; off = e - 49152; }
    else                { src = whh; dst = whb; off = e - 98304; }
    float4 a = *(const float4*)(src + off);
    float4 b = *(const float4*)(src + off + 4);
    uint4 r;
    r.x = (u32)f2b(a.x) | ((u32)f2b(a.y) << 16);
    r.y = (u32)f2b(a.z) | ((u32)f2b(a.w) << 16);
    r.z = (u32)f2b(b.x) | ((u32)f2b(b.y) << 16);
    r.w = (u32)f2b(b.z) | ((u32)f2b(b.w) << 16);
    *(uint4*)(dst + off) = r;
}

// ---------------- K2: per-batch mega kernel, 16 waves/block ----------------
// grid 256 (1 block/CU), 1024 thr: wave = (wr row-half, wc col-strip)
__global__ __launch_bounds__(1024,1) void k_mega(
    const int* __restrict__ pair, const int* __restrict__ relset,
    const int* __restrict__ path,
    const float* __restrict__ emb, const float* __restrict__ eu,
    const float* __restrict__ eub,
    const u16* __restrict__ wdb, const float* __restrict__ bd,
    const u16* __restrict__ web, const float* __restrict__ be,
    const u16* __restrict__ wpb, const float* __restrict__ bpv_,
    const u16* __restrict__ wib, const u16* __restrict__ whb,
    const float* __restrict__ bih, const float* __restrict__ bhh,
    float* __restrict__ out)
{
    __shared__ u16   Xs[GROWS*128];          // 48 KB rel tile (swizzled bf16)
    __shared__ u16   X2[GROWS*128];          // 48 KB cost-adjusted tile
    __shared__ u16   Hs[64*128];             // 16 KB GRU state
    __shared__ int   pS[GROWS];
    __shared__ float pdh[GROWS], pdt[GROWS], pdu[GROWS], pnn[GROWS];
    __shared__ float sdS[GROWS], seS[GROWS];
    __shared__ float s_hts, s_hi, s_ti;
    __shared__ float s_part[16];

    const int b    = blockIdx.x;
    const int tid  = threadIdx.x;
    const int wave = tid >> 6, lane = tid & 63;
    const int lrow = lane & 15, lk8 = lane >> 4;
    const int wc   = wave & 7, wr = wave >> 3;   // col strip / row half
    const int col  = wc*16 + lrow;
    const float eb = eub[0];

    // ---- P0: path indices + D/E weight fragments (hidden under gather) ----
    if (tid < GROWS) pS[tid] = path[b*GROWS + tid];
    bf16x8 fD[4], fE[4];
    #pragma unroll
    for (int ks = 0; ks < 4; ++ks) {
        const int gk = ks*4 + lk8;
        fD[ks] = ldg8(wdb + col*128 + gk*8);
        fE[ks] = ldg8(web + col*128 + gk*8);
    }
    const int ph = pair[2*b], ptl = pair[2*b+1];
    __syncthreads();

    // ---- P1: gather 192 rel rows -> Xs; pair stats; relset denom ----
    {
        #pragma unroll
        for (int i = 0; i < 3; ++i) {
            int gid = i*1024 + tid;             // 3072 granules of 8 bf16
            int r = gid >> 4, g = gid & 15;
            const float* sp = emb + (size_t)pS[r]*128 + g*8;
            float4 f0 = *(const float4*)sp;
            float4 f1 = *(const float4*)(sp + 4);
            bf16x8 v = pack8(f0.x,f0.y,f0.z,f0.w, f1.x,f1.y,f1.z,f1.w);
            *(uint4*)(&Xs[r*128 + ((g ^ (r & 7)) << 3)]) = __builtin_bit_cast(uint4, v);
        }
        if (wave == 0) {
            float2 hv2 = *(const float2*)(emb + (size_t)ph*128 + 2*lane);
            float2 tv2 = *(const float2*)(emb + (size_t)ptl*128 + 2*lane);
            float dht = hv2.x*tv2.x + hv2.y*tv2.y;
            float dhh = hv2.x*hv2.x + hv2.y*hv2.y;
            float dtt = tv2.x*tv2.x + tv2.y*tv2.y;
            #pragma unroll
            for (int o = 32; o > 0; o >>= 1) {
                dht += __shfl_xor(dht, o);
                dhh += __shfl_xor(dhh, o);
                dtt += __shfl_xor(dtt, o);
            }
            if (lane == 0) {
                float hn = 1.f / fmaxf(sqrtf(dhh), EPS_);
                float tn = 1.f / fmaxf(sqrtf(dtt), EPS_);
                s_hts = dht*hn*tn;
                s_hi  = hn;
                s_ti  = tn;
            }
        }
        // softmax denominator: 2 relset rows per wave (16 waves x 2 = 32)
        float2 uv2 = *(const float2*)(eu + 2*lane);
        float accs = 0.f;
        #pragma unroll
        for (int k = 0; k < 2; ++k) {
            const int ri = relset[b*R_ + wave*2 + k];
            float2 ev = *(const float2*)(emb + (size_t)ri*128 + 2*lane);
            float du = ev.x*uv2.x + ev.y*uv2.y;
            #pragma unroll
            for (int o = 32; o > 0; o >>= 1) du += __shfl_xor(du, o);
            accs += __expf(du + eb);
        }
        if (lane == 0) s_part[wave] = accs;
    }
    __syncthreads();

    // ---- P2: per-row partials from staged tile (16 lanes per row, 64 groups) ----
    {
        const int grp = tid >> 4;              // 0..63
        const int l16 = tid & 15;
        const float* hpq = emb + (size_t)ph*128  + l16*8;
        const float* tpq = emb + (size_t)ptl*128 + l16*8;
        const float* upq = eu + l16*8;
        float hq[8], tq[8], uq[8];
        {
            float4 a0 = *(const float4*)hpq, a1 = *(const float4*)(hpq+4);
            float4 b0 = *(const float4*)tpq, b1 = *(const float4*)(tpq+4);
            float4 c0 = *(const float4*)upq, c1 = *(const float4*)(upq+4);
            hq[0]=a0.x;hq[1]=a0.y;hq[2]=a0.z;hq[3]=a0.w;hq[4]=a1.x;hq[5]=a1.y;hq[6]=a1.z;hq[7]=a1.w;
            tq[0]=b0.x;tq[1]=b0.y;tq[2]=b0.z;tq[3]=b0.w;tq[4]=b1.x;tq[5]=b1.y;tq[6]=b1.z;tq[7]=b1.w;
            uq[0]=c0.x;uq[1]=c0.y;uq[2]=c0.z;uq[3]=c0.w;uq[4]=c1.x;uq[5]=c1.y;uq[6]=c1.z;uq[7]=c1.w;
        }
        #pragma unroll
        for (int i = 0; i < 3; ++i) {
            const int r = i*64 + grp;
            uint4 gv = *(const uint4*)(&Xs[r*128 + ((l16 ^ (r & 7)) << 3)]);
            float v[8];
            v[0]=b2f((u16)(gv.x&0xffff)); v[1]=b2f((u16)(gv.x>>16));
            v[2]=b2f((u16)(gv.y&0xffff)); v[3]=b2f((u16)(gv.y>>16));
            v[4]=b2f((u16)(gv.z&0xffff)); v[5]=b2f((u16)(gv.z>>16));
            v[6]=b2f((u16)(gv.w&0xffff)); v[7]=b2f((u16)(gv.w>>16));
            float dh=0.f, dt=0.f, du=0.f, nn=0.f;
            #pragma unroll
            for (int j = 0; j < 8; ++j) {
                dh = fmaf(v[j], hq[j], dh);
                dt = fmaf(v[j], tq[j], dt);
                du = fmaf(v[j], uq[j], du);
                nn = fmaf(v[j], v[j], nn);
            }
            #pragma unroll
            for (int o = 8; o > 0; o >>= 1) {
                dh += __shfl_xor(dh, o);
                dt += __shfl_xor(dt, o);
                du += __shfl_xor(du, o);
                nn += __shfl_xor(nn, o);
            }
            if (l16 == 0) { pdh[r]=dh; pdt[r]=dt; pdu[r]=du; pnn[r]=nn; }
        }
    }
    __syncthreads();

    // ---- P3: sd/se scalars (thread p = tid < 64) ----
    if (tid < 64) {
        float is = 0.f;
        #pragma unroll
        for (int w = 0; w < 16; ++w) is += s_part[w];
        is = 1.f/is;
        const float hi = s_hi, ti = s_ti, ht = s_hts;
        const int r1 = 3*tid, r2 = r1+1, r3 = r1+2;
        float n1i = 1.f / fmaxf(sqrtf(pnn[r1]), EPS_);
        float n2i = 1.f / fmaxf(sqrtf(pnn[r2]), EPS_);
        float se1 = 0.5f*(pdh[r1]*hi + pdt[r1]*ti)*n1i;
        float se2 = 0.5f*(pdh[r2]*hi + pdt[r2]*ti)*n2i;
        sdS[r1] = (1.f - 0.5f*(ht  + se1))*0.5f;
        sdS[r2] = (1.f - 0.5f*(se1 + se2))*0.5f;
        sdS[r3] = (1.f - 0.5f*(ht  + se2))*0.5f;
        seS[r1] = __expf(pdu[r1] + eb)*is;
        seS[r2] = __expf(pdu[r2] + eb)*is;
        seS[r3] = __expf(pdu[r3] + eb)*is;
    }
    __syncthreads();

    // ---- P4a: STREAMING D/E GEMM + cost epilogue -> X2 (rows split by wr) ----
    {
        const float bde = bd[col] + be[col];
        #pragma unroll 2
        for (int mt = 0; mt < 6; ++mt) {
            const int rbase = wr*96 + mt*16;
            f32x4 aD = (f32x4){0,0,0,0}, aE = (f32x4){0,0,0,0};
            #pragma unroll
            for (int ks = 0; ks < 4; ++ks) {
                const int gk = ks*4 + lk8;
                bf16x8 a = ldA(Xs, rbase + lrow, gk);
                aD = __builtin_amdgcn_mfma_f32_16x16x32_bf16(a, fD[ks], aD, 0,0,0);
                aE = __builtin_amdgcn_mfma_f32_16x16x32_bf16(a, fE[ks], aE, 0,0,0);
            }
            #pragma unroll
            for (int rr = 0; rr < 4; ++rr) {
                const int row = rbase + lk8*4 + rr;
                const int sl  = swz_slot(row, col);
                float relv = b2f(Xs[sl]);
                float c = sdS[row]*aD[rr] + seS[row]*aE[rr] + bde;
                X2[sl] = f2b(relv - 1e-3f*fmaxf(c, 0.f));
            }
        }
    }
    __syncthreads();   // X2 complete

    // ---- P4b: STREAMING P GEMM -> rel_in back into Xs ----
    {
        bf16x8 fP[4];
        #pragma unroll
        for (int ks = 0; ks < 4; ++ks)
            fP[ks] = ldg8(wpb + col*128 + (ks*4 + lk8)*8);
        const float bpv = bpv_[col];
        #pragma unroll 2
        for (int mt = 0; mt < 6; ++mt) {
            const int rbase = wr*96 + mt*16;
            f32x4 aP = (f32x4){0,0,0,0};
            #pragma unroll
            for (int ks = 0; ks < 4; ++ks) {
                const int gk = ks*4 + lk8;
                bf16x8 a = ldA(X2, rbase + lrow, gk);
                aP = __builtin_amdgcn_mfma_f32_16x16x32_bf16(a, fP[ks], aP, 0,0,0);
            }
            #pragma unroll
            for (int rr = 0; rr < 4; ++rr) {
                const int row = rbase + lk8*4 + rr;
                Xs[swz_slot(row, col)] = f2b(aP[rr] + bpv);
            }
        }
    }

    // ---- GRU x-side weight fragments: issue before barrier (latency hidden) ----
    bf16x8 wR[4], wZ[4], wI[4];
    #pragma unroll
    for (int ks = 0; ks < 4; ++ks) {
        const int gk = ks*4 + lk8;
        wR[ks] = ldg8(wib +           col*128 + gk*8);
        wZ[ks] = ldg8(wib + 16384   + col*128 + gk*8);
        wI[ks] = ldg8(wib + 2*16384 + col*128 + gk*8);
    }
    const float brv = bih[col]       + bhh[col];
    const float bzv = bih[128 + col] + bhh[128 + col];
    const float biN = bih[256 + col];
    const float bhN = bhh[256 + col];
    __syncthreads();   // Xs = rel_in complete

    // ---- P5: GRU over 64 bp rows (wr halves of 32); h-side reloaded per t ----
    float hreg[2][4];
    f32x4 aR[2], aZ[2], aI[2], aH[2];

    // t = 0 (h = 0)
    #pragma unroll
    for (int m = 0; m < 2; ++m) { aR[m]=(f32x4){0,0,0,0}; aZ[m]=(f32x4){0,0,0,0}; aI[m]=(f32x4){0,0,0,0}; }
    #pragma unroll
    for (int ks = 0; ks < 4; ++ks) {
        const int gk = ks*4 + lk8;
        #pragma unroll
        for (int mt = 0; mt < 2; ++mt) {
            bf16x8 ax = ldA(Xs, 3*(wr*32 + mt*16 + lrow) + 0, gk);
            aR[mt] = __builtin_amdgcn_mfma_f32_16x16x32_bf16(ax, wR[ks], aR[mt], 0,0,0);
            aZ[mt] = __builtin_amdgcn_mfma_f32_16x16x32_bf16(ax, wZ[ks], aZ[mt], 0,0,0);
            aI[mt] = __builtin_amdgcn_mfma_f32_16x16x32_bf16(ax, wI[ks], aI[mt], 0,0,0);
        }
    }
    #pragma unroll
    for (int mt = 0; mt < 2; ++mt)
        #pragma unroll
        for (int rr = 0; rr < 4; ++rr) {
            const int row = wr*32 + mt*16 + lk8*4 + rr;
            float rv = sigm_f(aR[mt][rr] + brv);
            float zv = sigm_f(aZ[mt][rr] + bzv);
            float nn = tanh_f(aI[mt][rr] + biN + rv*bhN);
            float h2 = (1.f - zv)*nn;
            hreg[mt][rr] = h2;
            Hs[swz_slot(row, col)] = f2b(h2);
        }
    __syncthreads();

    // t = 1, 2
    #pragma unroll
    for (int t = 1; t < 3; ++t) {
        #pragma unroll
        for (int m = 0; m < 2; ++m) { aR[m]=(f32x4){0,0,0,0}; aZ[m]=(f32x4){0,0,0,0}; aI[m]=(f32x4){0,0,0,0}; aH[m]=(f32x4){0,0,0,0}; }
        #pragma unroll
        for (int ks = 0; ks < 4; ++ks) {
            const int gk = ks*4 + lk8;
            bf16x8 vRk = ldg8(whb +           col*128 + gk*8);
            bf16x8 vZk = ldg8(whb + 16384   + col*128 + gk*8);
            bf16x8 vHk = ldg8(whb + 2*16384 + col*128 + gk*8);
            #pragma unroll
            for (int mt = 0; mt < 2; ++mt) {
                const int row = wr*32 + mt*16 + lrow;
                bf16x8 ax = ldA(Xs, 3*row + t, gk);
                bf16x8 ah = ldA(Hs, row, gk);
                aR[mt] = __builtin_amdgcn_mfma_f32_16x16x32_bf16(ax, wR[ks], aR[mt], 0,0,0);
                aZ[mt] = __builtin_amdgcn_mfma_f32_16x16x32_bf16(ax, wZ[ks], aZ[mt], 0,0,0);
                aI[mt] = __builtin_amdgcn_mfma_f32_16x16x32_bf16(ax, wI[ks], aI[mt], 0,0,0);
                aR[mt] = __builtin_amdgcn_mfma_f32_16x16x32_bf16(ah, vRk, aR[mt], 0,0,0);
                aZ[mt] = __builtin_amdgcn_mfma_f32_16x16x32_bf16(ah, vZk, aZ[mt], 0,0,0);
                aH[mt] = __builtin_amdgcn_mfma_f32_16x16x32_bf16(ah, vHk, aH[mt], 0,0,0);
            }
        }
        __syncthreads();              // all Hs reads of this step complete
        if (t < 2) {
            #pragma unroll
            for (int mt = 0; mt < 2; ++mt)
                #pragma unroll
                for (int rr = 0; rr < 4; ++rr) {
                    const int row = wr*32 + mt*16 + lk8*4 + rr;
                    float rv = sigm_f(aR[mt][rr] + brv);
                    float zv = sigm_f(aZ[mt][rr] + bzv);
                    float hn = aH[mt][rr] + bhN;
                    float nn = tanh_f(aI[mt][rr] + biN + rv*hn);
                    float h2 = (1.f - zv)*nn + zv*hreg[mt][rr];
                    hreg[mt][rr] = h2;
                    Hs[swz_slot(row, col)] = f2b(h2);
                }
            __syncthreads();
        } else {
            const int bp0 = b*64;
            #pragma unroll
            for (int mt = 0; mt < 2; ++mt)
                #pragma unroll
                for (int rr = 0; rr < 4; ++rr) {
                    const int row = wr*32 + mt*16 + lk8*4 + rr;
                    float rv = sigm_f(aR[mt][rr] + brv);
                    float zv = sigm_f(aZ[mt][rr] + bzv);
                    float hn = aH[mt][rr] + bhN;
                    float nn = tanh_f(aI[mt][rr] + biN + rv*hn);
                    float h2 = (1.f - zv)*nn + zv*hreg[mt][rr];
                    out[(size_t)(bp0 + row)*128 + col] = h2;
                }
        }
    }
}

extern "C" void kernel_launch(void* const* d_in, const int* in_sizes, int n_in,
                              void* d_out, int out_size, void* d_ws, size_t ws_size,
                              hipStream_t stream)
{
    const int*   path   = (const int*)d_in[0];
    const int*   pair   = (const int*)d_in[1];
    const int*   relset = (const int*)d_in[2];
    const float* emb    = (const float*)d_in[3];
    const float* wd     = (const float*)d_in[4];
    const float* bd     = (const float*)d_in[5];
    const float* we     = (const float*)d_in[6];
    const float* be     = (const float*)d_in[7];
    const float* wp     = (const float*)d_in[8];
    const float* bp     = (const float*)d_in[9];
    const float* eu     = (const float*)d_in[10];
    const float* eub    = (const float*)d_in[11];
    const float* wih    = (const float*)d_in[12];
    const float* whh    = (const float*)d_in[13];
    const float* bih    = (const float*)d_in[14];
    const float* bhh    = (const float*)d_in[15];
    float* out = (float*)d_out;
    float* ws  = (float*)d_ws;

    // workspace: only bf16 weights (~288 KB)
    u16* wdb = (u16*)ws;               // 16384 u16
    u16* web = wdb + 16384;
    u16* wpb = web + 16384;
    u16* wib = wpb + 16384;            // 49152 u16
    u16* whb = wib + 49152;            // ends at 147456 u16 = 288 KB

    k_wcvt<<<18, 1024, 0, stream>>>(wd, we, wp, wih, whh, wdb, web, wpb, wib, whb);
    k_mega<<<B_, 1024, 0, stream>>>(pair, relset, path, emb, eu, eub,
                                    wdb, bd, web, be, wpb, bp,
                                    wib, whb, bih, bhh, out);
}

// Round 15
// 68.848 us; speedup vs baseline: 1.0048x; 1.0048x over previous
//
#include <hip/hip_runtime.h>
#include <cmath>

#define D_ 128
#define B_ 256
#define P_ 64
#define R_ 32
#define GROWS 192        /* rel rows per batch block */
#define EPS_ 1e-8f

typedef unsigned short u16;
typedef unsigned int   u32;
using bf16x8 = __attribute__((ext_vector_type(8))) __bf16;
using f32x4  = __attribute__((ext_vector_type(4))) float;

__device__ __forceinline__ float sigm_f(float x){ return 1.0f/(1.0f + __expf(-x)); }
__device__ __forceinline__ float tanh_f(float x){
    float e = __expf(2.0f*x);
    return 1.0f - 2.0f/(e + 1.0f);
}

__device__ __forceinline__ u16 f2b(float f){         // fp32 -> bf16 RNE
    u32 u = __builtin_bit_cast(u32, f);
    u += 0x7fffu + ((u >> 16) & 1u);
    return (u16)(u >> 16);
}
__device__ __forceinline__ float b2f(u16 s){
    return __builtin_bit_cast(float, ((u32)s) << 16);
}
__device__ __forceinline__ bf16x8 pack8(float a0,float a1,float a2,float a3,
                                        float a4,float a5,float a6,float a7){
    uint4 r;
    r.x = (u32)f2b(a0) | ((u32)f2b(a1) << 16);
    r.y = (u32)f2b(a2) | ((u32)f2b(a3) << 16);
    r.z = (u32)f2b(a4) | ((u32)f2b(a5) << 16);
    r.w = (u32)f2b(a6) | ((u32)f2b(a7) << 16);
    return __builtin_bit_cast(bf16x8, r);
}
__device__ __forceinline__ bf16x8 ldg8(const u16* p){
    return __builtin_bit_cast(bf16x8, *(const uint4*)p);
}
// swizzled LDS bf16 tile: slot(row, granule g) at row*128 + ((g^(row&7))<<3)
__device__ __forceinline__ bf16x8 ldA(const u16* Xs, int row, int gk){
    return __builtin_bit_cast(bf16x8,
        *(const uint4*)(&Xs[row*128 + ((gk ^ (row & 7)) << 3)]));
}
__device__ __forceinline__ int swz_slot(int row, int col){
    return row*128 + (((col >> 3) ^ (row & 7)) << 3) + (col & 7);
}

// ---------------- K1: weight convert fp32 -> bf16 ----------------
__global__ __launch_bounds__(1024) void k_wcvt(
    const float* __restrict__ wd, const float* __restrict__ we,
    const float* __restrict__ wp, const float* __restrict__ wih,
    const float* __restrict__ whh,
    u16* __restrict__ wdb, u16* __restrict__ web, u16* __restrict__ wpb,
    u16* __restrict__ wib, u16* __restrict__ whb)
{
    int i = blockIdx.x*1024 + threadIdx.x;    // 0..18431
    int e = i*8;
    const float* src; u16* dst; int off;
    if      (e < 16384) { src = wd;  dst = wdb; off = e; }
    else if (e < 32768) { src = we;  dst = web; off = e - 16384; }
    else if (e < 49152) { src = wp;  dst = wpb; off = e - 32768; }
    else if (e < 98304) { src = wih; dst = wib; off = e - 49152; }
    else                { src = whh; dst = whb; off = e - 98304; }
    float4 a = *(const float4*)(src + off);
    float4 b = *(const float4*)(src + off + 4);
    uint4 r;
    r.x = (u32)f2b(a.x) | ((u32)f2b(a.y) << 16);
    r.y = (u32)f2b(a.z) | ((u32)f2b(a.w) << 16);
    r.z = (u32)f2b(b.x) | ((u32)f2b(b.y) << 16);
    r.w = (u32)f2b(b.z) | ((u32)f2b(b.w) << 16);
    *(uint4*)(dst + off) = r;
}

// ---------------- K2: per-batch mega kernel, 16 waves/block ----------------
// grid 256 (1 block/CU), 1024 thr: wave = (wr row-half, wc col-strip)
// __launch_bounds__(1024,4): 4 waves/EU = 16 waves/CU = 1 block -> 128-VGPR bin
__global__ __launch_bounds__(1024,4) void k_mega(
    const int* __restrict__ pair, const int* __restrict__ relset,
    const int* __restrict__ path,
    const float* __restrict__ emb, const float* __restrict__ eu,
    const float* __restrict__ eub,
    const u16* __restrict__ wdb, const float* __restrict__ bd,
    const u16* __restrict__ web, const float* __restrict__ be,
    const u16* __restrict__ wpb, const float* __restrict__ bpv_,
    const u16* __restrict__ wib, const u16* __restrict__ whb,
    const float* __restrict__ bih, const float* __restrict__ bhh,
    float* __restrict__ out)
{
    __shared__ u16   Xs[GROWS*128];          // 48 KB rel tile (swizzled bf16)
    __shared__ u16   X2[GROWS*128];          // 48 KB cost-adjusted tile
    __shared__ u16   Hs[64*128];             // 16 KB GRU state
    __shared__ int   pS[GROWS];
    __shared__ float pdh[GROWS], pdt[GROWS], pdu[GROWS], pnn[GROWS];
    __shared__ float sdS[GROWS], seS[GROWS];
    __shared__ float s_hts, s_hi, s_ti;
    __shared__ float s_part[16];

    const int b    = blockIdx.x;
    const int tid  = threadIdx.x;
    const int wave = tid >> 6, lane = tid & 63;
    const int lrow = lane & 15, lk8 = lane >> 4;
    const int wc   = wave & 7, wr = wave >> 3;   // col strip / row half
    const int col  = wc*16 + lrow;
    const float eb = eub[0];

    // ---- P0: path indices + D/E weight fragments (hidden under gather) ----
    if (tid < GROWS) pS[tid] = path[b*GROWS + tid];
    bf16x8 fD[4], fE[4];
    #pragma unroll
    for (int ks = 0; ks < 4; ++ks) {
        const int gk = ks*4 + lk8;
        fD[ks] = ldg8(wdb + col*128 + gk*8);
        fE[ks] = ldg8(web + col*128 + gk*8);
    }
    const int ph = pair[2*b], ptl = pair[2*b+1];
    __syncthreads();

    // ---- P1: gather 192 rel rows -> Xs; pair stats; relset denom ----
    {
        #pragma unroll
        for (int i = 0; i < 3; ++i) {
            int gid = i*1024 + tid;             // 3072 granules of 8 bf16
            int r = gid >> 4, g = gid & 15;
            const float* sp = emb + (size_t)pS[r]*128 + g*8;
            float4 f0 = *(const float4*)sp;
            float4 f1 = *(const float4*)(sp + 4);
            bf16x8 v = pack8(f0.x,f0.y,f0.z,f0.w, f1.x,f1.y,f1.z,f1.w);
            *(uint4*)(&Xs[r*128 + ((g ^ (r & 7)) << 3)]) = __builtin_bit_cast(uint4, v);
        }
        if (wave == 0) {
            float2 hv2 = *(const float2*)(emb + (size_t)ph*128 + 2*lane);
            float2 tv2 = *(const float2*)(emb + (size_t)ptl*128 + 2*lane);
            float dht = hv2.x*tv2.x + hv2.y*tv2.y;
            float dhh = hv2.x*hv2.x + hv2.y*hv2.y;
            float dtt = tv2.x*tv2.x + tv2.y*tv2.y;
            #pragma unroll
            for (int o = 32; o > 0; o >>= 1) {
                dht += __shfl_xor(dht, o);
                dhh += __shfl_xor(dhh, o);
                dtt += __shfl_xor(dtt, o);
            }
            if (lane == 0) {
                float hn = 1.f / fmaxf(sqrtf(dhh), EPS_);
                float tn = 1.f / fmaxf(sqrtf(dtt), EPS_);
                s_hts = dht*hn*tn;
                s_hi  = hn;
                s_ti  = tn;
            }
        }
        // softmax denominator: 2 relset rows per wave (16 waves x 2 = 32)
        float2 uv2 = *(const float2*)(eu + 2*lane);
        float accs = 0.f;
        #pragma unroll
        for (int k = 0; k < 2; ++k) {
            const int ri = relset[b*R_ + wave*2 + k];
            float2 ev = *(const float2*)(emb + (size_t)ri*128 + 2*lane);
            float du = ev.x*uv2.x + ev.y*uv2.y;
            #pragma unroll
            for (int o = 32; o > 0; o >>= 1) du += __shfl_xor(du, o);
            accs += __expf(du + eb);
        }
        if (lane == 0) s_part[wave] = accs;
    }
    __syncthreads();

    // ---- P2: per-row partials from staged tile (16 lanes per row, 64 groups) ----
    {
        const int grp = tid >> 4;              // 0..63
        const int l16 = tid & 15;
        const float* hpq = emb + (size_t)ph*128  + l16*8;
        const float* tpq = emb + (size_t)ptl*128 + l16*8;
        const float* upq = eu + l16*8;
        float hq[8], tq[8], uq[8];
        {
            float4 a0 = *(const float4*)hpq, a1 = *(const float4*)(hpq+4);
            float4 b0 = *(const float4*)tpq, b1 = *(const float4*)(tpq+4);
            float4 c0 = *(const float4*)upq, c1 = *(const float4*)(upq+4);
            hq[0]=a0.x;hq[1]=a0.y;hq[2]=a0.z;hq[3]=a0.w;hq[4]=a1.x;hq[5]=a1.y;hq[6]=a1.z;hq[7]=a1.w;
            tq[0]=b0.x;tq[1]=b0.y;tq[2]=b0.z;tq[3]=b0.w;tq[4]=b1.x;tq[5]=b1.y;tq[6]=b1.z;tq[7]=b1.w;
            uq[0]=c0.x;uq[1]=c0.y;uq[2]=c0.z;uq[3]=c0.w;uq[4]=c1.x;uq[5]=c1.y;uq[6]=c1.z;uq[7]=c1.w;
        }
        #pragma unroll
        for (int i = 0; i < 3; ++i) {
            const int r = i*64 + grp;
            uint4 gv = *(const uint4*)(&Xs[r*128 + ((l16 ^ (r & 7)) << 3)]);
            float v[8];
            v[0]=b2f((u16)(gv.x&0xffff)); v[1]=b2f((u16)(gv.x>>16));
            v[2]=b2f((u16)(gv.y&0xffff)); v[3]=b2f((u16)(gv.y>>16));
            v[4]=b2f((u16)(gv.z&0xffff)); v[5]=b2f((u16)(gv.z>>16));
            v[6]=b2f((u16)(gv.w&0xffff)); v[7]=b2f((u16)(gv.w>>16));
            float dh=0.f, dt=0.f, du=0.f, nn=0.f;
            #pragma unroll
            for (int j = 0; j < 8; ++j) {
                dh = fmaf(v[j], hq[j], dh);
                dt = fmaf(v[j], tq[j], dt);
                du = fmaf(v[j], uq[j], du);
                nn = fmaf(v[j], v[j], nn);
            }
            #pragma unroll
            for (int o = 8; o > 0; o >>= 1) {
                dh += __shfl_xor(dh, o);
                dt += __shfl_xor(dt, o);
                du += __shfl_xor(du, o);
                nn += __shfl_xor(nn, o);
            }
            if (l16 == 0) { pdh[r]=dh; pdt[r]=dt; pdu[r]=du; pnn[r]=nn; }
        }
    }
    __syncthreads();

    // ---- P3: sd/se scalars (thread p = tid < 64) ----
    if (tid < 64) {
        float is = 0.f;
        #pragma unroll
        for (int w = 0; w < 16; ++w) is += s_part[w];
        is = 1.f/is;
        const float hi = s_hi, ti = s_ti, ht = s_hts;
        const int r1 = 3*tid, r2 = r1+1, r3 = r1+2;
        float n1i = 1.f / fmaxf(sqrtf(pnn[r1]), EPS_);
        float n2i = 1.f / fmaxf(sqrtf(pnn[r2]), EPS_);
        float se1 = 0.5f*(pdh[r1]*hi + pdt[r1]*ti)*n1i;
        float se2 = 0.5f*(pdh[r2]*hi + pdt[r2]*ti)*n2i;
        sdS[r1] = (1.f - 0.5f*(ht  + se1))*0.5f;
        sdS[r2] = (1.f - 0.5f*(se1 + se2))*0.5f;
        sdS[r3] = (1.f - 0.5f*(ht  + se2))*0.5f;
        seS[r1] = __expf(pdu[r1] + eb)*is;
        seS[r2] = __expf(pdu[r2] + eb)*is;
        seS[r3] = __expf(pdu[r3] + eb)*is;
    }
    __syncthreads();

    // ---- P4a: STREAMING D/E GEMM + cost epilogue -> X2 (rows split by wr) ----
    {
        const float bde = bd[col] + be[col];
        #pragma unroll 2
        for (int mt = 0; mt < 6; ++mt) {
            const int rbase = wr*96 + mt*16;
            f32x4 aD = (f32x4){0,0,0,0}, aE = (f32x4){0,0,0,0};
            #pragma unroll
            for (int ks = 0; ks < 4; ++ks) {
                const int gk = ks*4 + lk8;
                bf16x8 a = ldA(Xs, rbase + lrow, gk);
                aD = __builtin_amdgcn_mfma_f32_16x16x32_bf16(a, fD[ks], aD, 0,0,0);
                aE = __builtin_amdgcn_mfma_f32_16x16x32_bf16(a, fE[ks], aE, 0,0,0);
            }
            #pragma unroll
            for (int rr = 0; rr < 4; ++rr) {
                const int row = rbase + lk8*4 + rr;
                const int sl  = swz_slot(row, col);
                float relv = b2f(Xs[sl]);
                float c = sdS[row]*aD[rr] + seS[row]*aE[rr] + bde;
                X2[sl] = f2b(relv - 1e-3f*fmaxf(c, 0.f));
            }
        }
    }
    __syncthreads();   // X2 complete

    // ---- P4b: STREAMING P GEMM -> rel_in back into Xs ----
    {
        bf16x8 fP[4];
        #pragma unroll
        for (int ks = 0; ks < 4; ++ks)
            fP[ks] = ldg8(wpb + col*128 + (ks*4 + lk8)*8);
        const float bpv = bpv_[col];
        #pragma unroll 2
        for (int mt = 0; mt < 6; ++mt) {
            const int rbase = wr*96 + mt*16;
            f32x4 aP = (f32x4){0,0,0,0};
            #pragma unroll
            for (int ks = 0; ks < 4; ++ks) {
                const int gk = ks*4 + lk8;
                bf16x8 a = ldA(X2, rbase + lrow, gk);
                aP = __builtin_amdgcn_mfma_f32_16x16x32_bf16(a, fP[ks], aP, 0,0,0);
            }
            #pragma unroll
            for (int rr = 0; rr < 4; ++rr) {
                const int row = rbase + lk8*4 + rr;
                Xs[swz_slot(row, col)] = f2b(aP[rr] + bpv);
            }
        }
    }

    // ---- GRU x-side weight fragments: issue before barrier (latency hidden) ----
    bf16x8 wR[4], wZ[4], wI[4];
    #pragma unroll
    for (int ks = 0; ks < 4; ++ks) {
        const int gk = ks*4 + lk8;
        wR[ks] = ldg8(wib +           col*128 + gk*8);
        wZ[ks] = ldg8(wib + 16384   + col*128 + gk*8);
        wI[ks] = ldg8(wib + 2*16384 + col*128 + gk*8);
    }
    const float brv = bih[col]       + bhh[col];
    const float bzv = bih[128 + col] + bhh[128 + col];
    const float biN = bih[256 + col];
    const float bhN = bhh[256 + col];
    __syncthreads();   // Xs = rel_in complete

    // ---- P5: GRU over 64 bp rows (wr halves of 32); h-side reloaded per t ----
    float hreg[2][4];
    f32x4 aR[2], aZ[2], aI[2], aH[2];

    // t = 0 (h = 0)
    #pragma unroll
    for (int m = 0; m < 2; ++m) { aR[m]=(f32x4){0,0,0,0}; aZ[m]=(f32x4){0,0,0,0}; aI[m]=(f32x4){0,0,0,0}; }
    #pragma unroll
    for (int ks = 0; ks < 4; ++ks) {
        const int gk = ks*4 + lk8;
        #pragma unroll
        for (int mt = 0; mt < 2; ++mt) {
            bf16x8 ax = ldA(Xs, 3*(wr*32 + mt*16 + lrow) + 0, gk);
            aR[mt] = __builtin_amdgcn_mfma_f32_16x16x32_bf16(ax, wR[ks], aR[mt], 0,0,0);
            aZ[mt] = __builtin_amdgcn_mfma_f32_16x16x32_bf16(ax, wZ[ks], aZ[mt], 0,0,0);
            aI[mt] = __builtin_amdgcn_mfma_f32_16x16x32_bf16(ax, wI[ks], aI[mt], 0,0,0);
        }
    }
    #pragma unroll
    for (int mt = 0; mt < 2; ++mt)
        #pragma unroll
        for (int rr = 0; rr < 4; ++rr) {
            const int row = wr*32 + mt*16 + lk8*4 + rr;
            float rv = sigm_f(aR[mt][rr] + brv);
            float zv = sigm_f(aZ[mt][rr] + bzv);
            float nn = tanh_f(aI[mt][rr] + biN + rv*bhN);
            float h2 = (1.f - zv)*nn;
            hreg[mt][rr] = h2;
            Hs[swz_slot(row, col)] = f2b(h2);
        }
    __syncthreads();

    // t = 1, 2
    #pragma unroll
    for (int t = 1; t < 3; ++t) {
        #pragma unroll
        for (int m = 0; m < 2; ++m) { aR[m]=(f32x4){0,0,0,0}; aZ[m]=(f32x4){0,0,0,0}; aI[m]=(f32x4){0,0,0,0}; aH[m]=(f32x4){0,0,0,0}; }
        #pragma unroll
        for (int ks = 0; ks < 4; ++ks) {
            const int gk = ks*4 + lk8;
            bf16x8 vRk = ldg8(whb +           col*128 + gk*8);
            bf16x8 vZk = ldg8(whb + 16384   + col*128 + gk*8);
            bf16x8 vHk = ldg8(whb + 2*16384 + col*128 + gk*8);
            #pragma unroll
            for (int mt = 0; mt < 2; ++mt) {
                const int row = wr*32 + mt*16 + lrow;
                bf16x8 ax = ldA(Xs, 3*row + t, gk);
                bf16x8 ah = ldA(Hs, row, gk);
                aR[mt] = __builtin_amdgcn_mfma_f32_16x16x32_bf16(ax, wR[ks], aR[mt], 0,0,0);
                aZ[mt] = __builtin_amdgcn_mfma_f32_16x16x32_bf16(ax, wZ[ks], aZ[mt], 0,0,0);
                aI[mt] = __builtin_amdgcn_mfma_f32_16x16x32_bf16(ax, wI[ks], aI[mt], 0,0,0);
                aR[mt] = __builtin_amdgcn_mfma_f32_16x16x32_bf16(ah, vRk, aR[mt], 0,0,0);
                aZ[mt] = __builtin_amdgcn_mfma_f32_16x16x32_bf16(ah, vZk, aZ[mt], 0,0,0);
                aH[mt] = __builtin_amdgcn_mfma_f32_16x16x32_bf16(ah, vHk, aH[mt], 0,0,0);
            }
        }
        __syncthreads();              // all Hs reads of this step complete
        if (t < 2) {
            #pragma unroll
            for (int mt = 0; mt < 2; ++mt)
                #pragma unroll
                for (int rr = 0; rr < 4; ++rr) {
                    const int row = wr*32 + mt*16 + lk8*4 + rr;
                    float rv = sigm_f(aR[mt][rr] + brv);
                    float zv = sigm_f(aZ[mt][rr] + bzv);
                    float hn = aH[mt][rr] + bhN;
                    float nn = tanh_f(aI[mt][rr] + biN + rv*hn);
                    float h2 = (1.f - zv)*nn + zv*hreg[mt][rr];
                    hreg[mt][rr] = h2;
                    Hs[swz_slot(row, col)] = f2b(h2);
                }
            __syncthreads();
        } else {
            const int bp0 = b*64;
            #pragma unroll
            for (int mt = 0; mt < 2; ++mt)
                #pragma unroll
                for (int rr = 0; rr < 4; ++rr) {
                    const int row = wr*32 + mt*16 + lk8*4 + rr;
                    float rv = sigm_f(aR[mt][rr] + brv);
                    float zv = sigm_f(aZ[mt][rr] + bzv);
                    float hn = aH[mt][rr] + bhN;
                    float nn = tanh_f(aI[mt][rr] + biN + rv*hn);
                    float h2 = (1.f - zv)*nn + zv*hreg[mt][rr];
                    out[(size_t)(bp0 + row)*128 + col] = h2;
                }
        }
    }
}

extern "C" void kernel_launch(void* const* d_in, const int* in_sizes, int n_in,
                              void* d_out, int out_size, void* d_ws, size_t ws_size,
                              hipStream_t stream)
{
    const int*   path   = (const int*)d_in[0];
    const int*   pair   = (const int*)d_in[1];
    const int*   relset = (const int*)d_in[2];
    const float* emb    = (const float*)d_in[3];
    const float* wd     = (const float*)d_in[4];
    const float* bd     = (const float*)d_in[5];
    const float* we     = (const float*)d_in[6];
    const float* be     = (const float*)d_in[7];
    const float* wp     = (const float*)d_in[8];
    const float* bp     = (const float*)d_in[9];
    const float* eu     = (const float*)d_in[10];
    const float* eub    = (const float*)d_in[11];
    const float* wih    = (const float*)d_in[12];
    const float* whh    = (const float*)d_in[13];
    const float* bih    = (const float*)d_in[14];
    const float* bhh    = (const float*)d_in[15];
    float* out = (float*)d_out;
    float* ws  = (float*)d_ws;

    // workspace: only bf16 weights (~288 KB)
    u16* wdb = (u16*)ws;               // 16384 u16
    u16* web = wdb + 16384;
    u16* wpb = web + 16384;
    u16* wib = wpb + 16384;            // 49152 u16
    u16* whb = wib + 49152;            // ends at 147456 u16 = 288 KB

    k_wcvt<<<18, 1024, 0, stream>>>(wd, we, wp, wih, whh, wdb, web, wpb, wib, whb);
    k_mega<<<B_, 1024, 0, stream>>>(pair, relset, path, emb, eu, eub,
                                    wdb, bd, web, be, wpb, bp,
                                    wib, whb, bih, bhh, out);
}

// Round 16
// 53.983 us; speedup vs baseline: 1.2815x; 1.2754x over previous
//
#include <hip/hip_runtime.h>
#include <cmath>

#define D_ 128
#define B_ 256
#define P_ 64
#define R_ 32
#define GROWS 192        /* rel rows per batch block */
#define EPS_ 1e-8f

typedef unsigned short u16;
typedef unsigned int   u32;
using bf16x8 = __attribute__((ext_vector_type(8))) __bf16;
using f32x4  = __attribute__((ext_vector_type(4))) float;

__device__ __forceinline__ float sigm_f(float x){ return 1.0f/(1.0f + __expf(-x)); }
__device__ __forceinline__ float tanh_f(float x){
    float e = __expf(2.0f*x);
    return 1.0f - 2.0f/(e + 1.0f);
}

__device__ __forceinline__ u16 f2b(float f){         // fp32 -> bf16 RNE
    u32 u = __builtin_bit_cast(u32, f);
    u += 0x7fffu + ((u >> 16) & 1u);
    return (u16)(u >> 16);
}
__device__ __forceinline__ float b2f(u16 s){
    return __builtin_bit_cast(float, ((u32)s) << 16);
}
__device__ __forceinline__ bf16x8 pack8(float a0,float a1,float a2,float a3,
                                        float a4,float a5,float a6,float a7){
    uint4 r;
    r.x = (u32)f2b(a0) | ((u32)f2b(a1) << 16);
    r.y = (u32)f2b(a2) | ((u32)f2b(a3) << 16);
    r.z = (u32)f2b(a4) | ((u32)f2b(a5) << 16);
    r.w = (u32)f2b(a6) | ((u32)f2b(a7) << 16);
    return __builtin_bit_cast(bf16x8, r);
}
// build a bf16x8 MFMA fragment directly from 8 consecutive fp32 values (L2-hot)
__device__ __forceinline__ bf16x8 ldw8(const float* p){
    float4 a = *(const float4*)p;
    float4 b = *(const float4*)(p + 4);
    return pack8(a.x,a.y,a.z,a.w, b.x,b.y,b.z,b.w);
}
// swizzled LDS bf16 tile: slot(row, granule g) at row*128 + ((g^(row&7))<<3)
__device__ __forceinline__ bf16x8 ldA(const u16* Xs, int row, int gk){
    return __builtin_bit_cast(bf16x8,
        *(const uint4*)(&Xs[row*128 + ((gk ^ (row & 7)) << 3)]));
}
__device__ __forceinline__ int swz_slot(int row, int col){
    return row*128 + (((col >> 3) ^ (row & 7)) << 3) + (col & 7);
}

// ---------------- single mega kernel: one batch per block ----------------
// grid 256, 512 thr (8 waves x 16-col strips); weights converted inline (no k_wcvt)
__global__ __launch_bounds__(512,2) void k_mega(
    const int* __restrict__ pair, const int* __restrict__ relset,
    const int* __restrict__ path,
    const float* __restrict__ emb, const float* __restrict__ eu,
    const float* __restrict__ eub,
    const float* __restrict__ wd, const float* __restrict__ bd,
    const float* __restrict__ we, const float* __restrict__ be,
    const float* __restrict__ wp, const float* __restrict__ bpv_,
    const float* __restrict__ wih, const float* __restrict__ whh,
    const float* __restrict__ bih, const float* __restrict__ bhh,
    float* __restrict__ out)
{
    __shared__ u16   Xs[GROWS*128];          // 48 KB rel tile (swizzled bf16)
    __shared__ u16   X2[GROWS*128];          // 48 KB cost-adjusted tile
    __shared__ u16   Hs[64*128];             // 16 KB GRU state
    __shared__ int   pS[GROWS];
    __shared__ float pdh[GROWS], pdt[GROWS], pdu[GROWS], pnn[GROWS];
    __shared__ float sdS[GROWS], seS[GROWS];
    __shared__ float s_hts, s_hi, s_ti;
    __shared__ float s_part[8];

    const int b    = blockIdx.x;
    const int tid  = threadIdx.x;
    const int wave = tid >> 6, lane = tid & 63;
    const int lrow = lane & 15, lk8 = lane >> 4;
    const int col  = wave*16 + lrow;
    const float eb = eub[0];

    // ---- P0: path indices + D/E weight fragments (inline fp32->bf16) ----
    if (tid < GROWS) pS[tid] = path[b*GROWS + tid];
    bf16x8 fD[4], fE[4];
    #pragma unroll
    for (int ks = 0; ks < 4; ++ks) {
        const int gk = ks*4 + lk8;
        fD[ks] = ldw8(wd + col*128 + gk*8);
        fE[ks] = ldw8(we + col*128 + gk*8);
    }
    const int ph = pair[2*b], ptl = pair[2*b+1];
    __syncthreads();

    // ---- P1: gather 192 rel rows -> Xs; pair stats; relset denom ----
    {
        #pragma unroll
        for (int i = 0; i < 6; ++i) {
            int gid = i*512 + tid;              // 3072 granules of 8 bf16
            int r = gid >> 4, g = gid & 15;
            const float* sp = emb + (size_t)pS[r]*128 + g*8;
            float4 f0 = *(const float4*)sp;
            float4 f1 = *(const float4*)(sp + 4);
            bf16x8 v = pack8(f0.x,f0.y,f0.z,f0.w, f1.x,f1.y,f1.z,f1.w);
            *(uint4*)(&Xs[r*128 + ((g ^ (r & 7)) << 3)]) = __builtin_bit_cast(uint4, v);
        }
        if (wave == 0) {
            float2 hv2 = *(const float2*)(emb + (size_t)ph*128 + 2*lane);
            float2 tv2 = *(const float2*)(emb + (size_t)ptl*128 + 2*lane);
            float dht = hv2.x*tv2.x + hv2.y*tv2.y;
            float dhh = hv2.x*hv2.x + hv2.y*hv2.y;
            float dtt = tv2.x*tv2.x + tv2.y*tv2.y;
            #pragma unroll
            for (int o = 32; o > 0; o >>= 1) {
                dht += __shfl_xor(dht, o);
                dhh += __shfl_xor(dhh, o);
                dtt += __shfl_xor(dtt, o);
            }
            if (lane == 0) {
                float hn = 1.f / fmaxf(sqrtf(dhh), EPS_);
                float tn = 1.f / fmaxf(sqrtf(dtt), EPS_);
                s_hts = dht*hn*tn;
                s_hi  = hn;
                s_ti  = tn;
            }
        }
        // softmax denominator: 4 relset rows per wave
        float2 uv2 = *(const float2*)(eu + 2*lane);
        float accs = 0.f;
        #pragma unroll
        for (int k = 0; k < 4; ++k) {
            const int ri = relset[b*R_ + wave*4 + k];
            float2 ev = *(const float2*)(emb + (size_t)ri*128 + 2*lane);
            float du = ev.x*uv2.x + ev.y*uv2.y;
            #pragma unroll
            for (int o = 32; o > 0; o >>= 1) du += __shfl_xor(du, o);
            accs += __expf(du + eb);
        }
        if (lane == 0) s_part[wave] = accs;
    }
    __syncthreads();

    // ---- P2: per-row partials from staged tile (16 lanes per row) ----
    {
        const int sub = lane >> 4, l16 = lane & 15;
        const float* hpq = emb + (size_t)ph*128  + l16*8;
        const float* tpq = emb + (size_t)ptl*128 + l16*8;
        const float* upq = eu + l16*8;
        float hq[8], tq[8], uq[8];
        {
            float4 a0 = *(const float4*)hpq, a1 = *(const float4*)(hpq+4);
            float4 b0 = *(const float4*)tpq, b1 = *(const float4*)(tpq+4);
            float4 c0 = *(const float4*)upq, c1 = *(const float4*)(upq+4);
            hq[0]=a0.x;hq[1]=a0.y;hq[2]=a0.z;hq[3]=a0.w;hq[4]=a1.x;hq[5]=a1.y;hq[6]=a1.z;hq[7]=a1.w;
            tq[0]=b0.x;tq[1]=b0.y;tq[2]=b0.z;tq[3]=b0.w;tq[4]=b1.x;tq[5]=b1.y;tq[6]=b1.z;tq[7]=b1.w;
            uq[0]=c0.x;uq[1]=c0.y;uq[2]=c0.z;uq[3]=c0.w;uq[4]=c1.x;uq[5]=c1.y;uq[6]=c1.z;uq[7]=c1.w;
        }
        #pragma unroll
        for (int i = 0; i < 6; ++i) {
            const int r = wave*24 + i*4 + sub;
            uint4 gv = *(const uint4*)(&Xs[r*128 + ((l16 ^ (r & 7)) << 3)]);
            float v[8];
            v[0]=b2f((u16)(gv.x&0xffff)); v[1]=b2f((u16)(gv.x>>16));
            v[2]=b2f((u16)(gv.y&0xffff)); v[3]=b2f((u16)(gv.y>>16));
            v[4]=b2f((u16)(gv.z&0xffff)); v[5]=b2f((u16)(gv.z>>16));
            v[6]=b2f((u16)(gv.w&0xffff)); v[7]=b2f((u16)(gv.w>>16));
            float dh=0.f, dt=0.f, du=0.f, nn=0.f;
            #pragma unroll
            for (int j = 0; j < 8; ++j) {
                dh = fmaf(v[j], hq[j], dh);
                dt = fmaf(v[j], tq[j], dt);
                du = fmaf(v[j], uq[j], du);
                nn = fmaf(v[j], v[j], nn);
            }
            #pragma unroll
            for (int o = 8; o > 0; o >>= 1) {
                dh += __shfl_xor(dh, o);
                dt += __shfl_xor(dt, o);
                du += __shfl_xor(du, o);
                nn += __shfl_xor(nn, o);
            }
            if (l16 == 0) { pdh[r]=dh; pdt[r]=dt; pdu[r]=du; pnn[r]=nn; }
        }
    }
    __syncthreads();

    // ---- P3: sd/se scalars (thread p = tid < 64) ----
    if (tid < 64) {
        float is = 0.f;
        #pragma unroll
        for (int w = 0; w < 8; ++w) is += s_part[w];
        is = 1.f/is;
        const float hi = s_hi, ti = s_ti, ht = s_hts;
        const int r1 = 3*tid, r2 = r1+1, r3 = r1+2;
        float n1i = 1.f / fmaxf(sqrtf(pnn[r1]), EPS_);
        float n2i = 1.f / fmaxf(sqrtf(pnn[r2]), EPS_);
        float se1 = 0.5f*(pdh[r1]*hi + pdt[r1]*ti)*n1i;
        float se2 = 0.5f*(pdh[r2]*hi + pdt[r2]*ti)*n2i;
        sdS[r1] = (1.f - 0.5f*(ht  + se1))*0.5f;
        sdS[r2] = (1.f - 0.5f*(se1 + se2))*0.5f;
        sdS[r3] = (1.f - 0.5f*(ht  + se2))*0.5f;
        seS[r1] = __expf(pdu[r1] + eb)*is;
        seS[r2] = __expf(pdu[r2] + eb)*is;
        seS[r3] = __expf(pdu[r3] + eb)*is;
    }
    __syncthreads();

    // ---- P4a: STREAMING D/E GEMM + cost epilogue -> X2 (no mid barriers) ----
    {
        const float bde = bd[col] + be[col];
        #pragma unroll 2
        for (int mt = 0; mt < 12; ++mt) {
            f32x4 aD = (f32x4){0,0,0,0}, aE = (f32x4){0,0,0,0};
            #pragma unroll
            for (int ks = 0; ks < 4; ++ks) {
                const int gk = ks*4 + lk8;
                bf16x8 a = ldA(Xs, mt*16 + lrow, gk);
                aD = __builtin_amdgcn_mfma_f32_16x16x32_bf16(a, fD[ks], aD, 0,0,0);
                aE = __builtin_amdgcn_mfma_f32_16x16x32_bf16(a, fE[ks], aE, 0,0,0);
            }
            #pragma unroll
            for (int rr = 0; rr < 4; ++rr) {
                const int row = mt*16 + lk8*4 + rr;
                const int sl  = swz_slot(row, col);
                float relv = b2f(Xs[sl]);
                float c = sdS[row]*aD[rr] + seS[row]*aE[rr] + bde;
                X2[sl] = f2b(relv - 1e-3f*fmaxf(c, 0.f));
            }
        }
    }
    __syncthreads();   // X2 complete

    // ---- P4b: STREAMING P GEMM -> rel_in back into Xs ----
    {
        bf16x8 fP[4];
        #pragma unroll
        for (int ks = 0; ks < 4; ++ks)
            fP[ks] = ldw8(wp + col*128 + (ks*4 + lk8)*8);
        const float bpv = bpv_[col];
        #pragma unroll 2
        for (int mt = 0; mt < 12; ++mt) {
            f32x4 aP = (f32x4){0,0,0,0};
            #pragma unroll
            for (int ks = 0; ks < 4; ++ks) {
                const int gk = ks*4 + lk8;
                bf16x8 a = ldA(X2, mt*16 + lrow, gk);
                aP = __builtin_amdgcn_mfma_f32_16x16x32_bf16(a, fP[ks], aP, 0,0,0);
            }
            #pragma unroll
            for (int rr = 0; rr < 4; ++rr) {
                const int row = mt*16 + lk8*4 + rr;
                Xs[swz_slot(row, col)] = f2b(aP[rr] + bpv);
            }
        }
    }

    // ---- GRU x-side weight fragments: convert before barrier (latency hidden) ----
    bf16x8 wR[4], wZ[4], wI[4];
    #pragma unroll
    for (int ks = 0; ks < 4; ++ks) {
        const int gk = ks*4 + lk8;
        wR[ks] = ldw8(wih + (size_t)(      col)*128 + gk*8);
        wZ[ks] = ldw8(wih + (size_t)(128 + col)*128 + gk*8);
        wI[ks] = ldw8(wih + (size_t)(256 + col)*128 + gk*8);
    }
    const float brv = bih[col]       + bhh[col];
    const float bzv = bih[128 + col] + bhh[128 + col];
    const float biN = bih[256 + col];
    const float bhN = bhh[256 + col];
    __syncthreads();   // Xs = rel_in complete

    // ---- P5: GRU over 64 bp rows; h-side weights converted per t (L2-hot fp32) ----
    float hreg[4][4];
    f32x4 aR[4], aZ[4], aI[4], aH[4];

    // t = 0 (h = 0)
    #pragma unroll
    for (int m = 0; m < 4; ++m) { aR[m]=(f32x4){0,0,0,0}; aZ[m]=(f32x4){0,0,0,0}; aI[m]=(f32x4){0,0,0,0}; }
    #pragma unroll
    for (int ks = 0; ks < 4; ++ks) {
        const int gk = ks*4 + lk8;
        #pragma unroll
        for (int mt = 0; mt < 4; ++mt) {
            bf16x8 ax = ldA(Xs, 3*(mt*16 + lrow) + 0, gk);
            aR[mt] = __builtin_amdgcn_mfma_f32_16x16x32_bf16(ax, wR[ks], aR[mt], 0,0,0);
            aZ[mt] = __builtin_amdgcn_mfma_f32_16x16x32_bf16(ax, wZ[ks], aZ[mt], 0,0,0);
            aI[mt] = __builtin_amdgcn_mfma_f32_16x16x32_bf16(ax, wI[ks], aI[mt], 0,0,0);
        }
    }
    #pragma unroll
    for (int mt = 0; mt < 4; ++mt)
        #pragma unroll
        for (int rr = 0; rr < 4; ++rr) {
            const int row = mt*16 + lk8*4 + rr;
            float rv = sigm_f(aR[mt][rr] + brv);
            float zv = sigm_f(aZ[mt][rr] + bzv);
            float nn = tanh_f(aI[mt][rr] + biN + rv*bhN);
            float h2 = (1.f - zv)*nn;
            hreg[mt][rr] = h2;
            Hs[swz_slot(row, col)] = f2b(h2);
        }
    __syncthreads();

    // t = 1, 2
    #pragma unroll
    for (int t = 1; t < 3; ++t) {
        #pragma unroll
        for (int m = 0; m < 4; ++m) { aR[m]=(f32x4){0,0,0,0}; aZ[m]=(f32x4){0,0,0,0}; aI[m]=(f32x4){0,0,0,0}; aH[m]=(f32x4){0,0,0,0}; }
        #pragma unroll
        for (int ks = 0; ks < 4; ++ks) {
            const int gk = ks*4 + lk8;
            bf16x8 vRk = ldw8(whh + (size_t)(      col)*128 + gk*8);
            bf16x8 vZk = ldw8(whh + (size_t)(128 + col)*128 + gk*8);
            bf16x8 vHk = ldw8(whh + (size_t)(256 + col)*128 + gk*8);
            #pragma unroll
            for (int mt = 0; mt < 4; ++mt) {
                bf16x8 ax = ldA(Xs, 3*(mt*16 + lrow) + t, gk);
                bf16x8 ah = ldA(Hs, mt*16 + lrow, gk);
                aR[mt] = __builtin_amdgcn_mfma_f32_16x16x32_bf16(ax, wR[ks], aR[mt], 0,0,0);
                aZ[mt] = __builtin_amdgcn_mfma_f32_16x16x32_bf16(ax, wZ[ks], aZ[mt], 0,0,0);
                aI[mt] = __builtin_amdgcn_mfma_f32_16x16x32_bf16(ax, wI[ks], aI[mt], 0,0,0);
                aR[mt] = __builtin_amdgcn_mfma_f32_16x16x32_bf16(ah, vRk, aR[mt], 0,0,0);
                aZ[mt] = __builtin_amdgcn_mfma_f32_16x16x32_bf16(ah, vZk, aZ[mt], 0,0,0);
                aH[mt] = __builtin_amdgcn_mfma_f32_16x16x32_bf16(ah, vHk, aH[mt], 0,0,0);
            }
        }
        __syncthreads();              // all Hs reads of this step complete
        if (t < 2) {
            #pragma unroll
            for (int mt = 0; mt < 4; ++mt)
                #pragma unroll
                for (int rr = 0; rr < 4; ++rr) {
                    const int row = mt*16 + lk8*4 + rr;
                    float rv = sigm_f(aR[mt][rr] + brv);
                    float zv = sigm_f(aZ[mt][rr] + bzv);
                    float hn = aH[mt][rr] + bhN;
                    float nn = tanh_f(aI[mt][rr] + biN + rv*hn);
                    float h2 = (1.f - zv)*nn + zv*hreg[mt][rr];
                    hreg[mt][rr] = h2;
                    Hs[swz_slot(row, col)] = f2b(h2);
                }
            __syncthreads();
        } else {
            const int bp0 = b*64;
            #pragma unroll
            for (int mt = 0; mt < 4; ++mt)
                #pragma unroll
                for (int rr = 0; rr < 4; ++rr) {
                    const int row = mt*16 + lk8*4 + rr;
                    float rv = sigm_f(aR[mt][rr] + brv);
                    float zv = sigm_f(aZ[mt][rr] + bzv);
                    float hn = aH[mt][rr] + bhN;
                    float nn = tanh_f(aI[mt][rr] + biN + rv*hn);
                    float h2 = (1.f - zv)*nn + zv*hreg[mt][rr];
                    out[(size_t)(bp0 + row)*128 + col] = h2;
                }
        }
    }
}

extern "C" void kernel_launch(void* const* d_in, const int* in_sizes, int n_in,
                              void* d_out, int out_size, void* d_ws, size_t ws_size,
                              hipStream_t stream)
{
    const int*   path   = (const int*)d_in[0];
    const int*   pair   = (const int*)d_in[1];
    const int*   relset = (const int*)d_in[2];
    const float* emb    = (const float*)d_in[3];
    const float* wd     = (const float*)d_in[4];
    const float* bd     = (const float*)d_in[5];
    const float* we     = (const float*)d_in[6];
    const float* be     = (const float*)d_in[7];
    const float* wp     = (const float*)d_in[8];
    const float* bp     = (const float*)d_in[9];
    const float* eu     = (const float*)d_in[10];
    const float* eub    = (const float*)d_in[11];
    const float* wih    = (const float*)d_in[12];
    const float* whh    = (const float*)d_in[13];
    const float* bih    = (const float*)d_in[14];
    const float* bhh    = (const float*)d_in[15];
    float* out = (float*)d_out;

    k_mega<<<B_, 512, 0, stream>>>(pair, relset, path, emb, eu, eub,
                                   wd, bd, we, be, wp, bp,
                                   wih, whh, bih, bhh, out);
}

// Round 17
// 44.381 us; speedup vs baseline: 1.5588x; 1.2164x over previous
//
#include <hip/hip_runtime.h>
#include <cmath>

#define D_ 128
#define B_ 256
#define P_ 64
#define R_ 32
#define GROWS 192        /* rel rows per batch block */
#define EPS_ 1e-8f

typedef unsigned short u16;
typedef unsigned int   u32;
using bf16x8 = __attribute__((ext_vector_type(8))) __bf16;
using f32x4  = __attribute__((ext_vector_type(4))) float;

__device__ __forceinline__ float sigm_f(float x){ return 1.0f/(1.0f + __expf(-x)); }
__device__ __forceinline__ float tanh_f(float x){
    float e = __expf(2.0f*x);
    return 1.0f - 2.0f/(e + 1.0f);
}

__device__ __forceinline__ u16 f2b(float f){         // fp32 -> bf16 RNE
    u32 u = __builtin_bit_cast(u32, f);
    u += 0x7fffu + ((u >> 16) & 1u);
    return (u16)(u >> 16);
}
__device__ __forceinline__ float b2f(u16 s){
    return __builtin_bit_cast(float, ((u32)s) << 16);
}
__device__ __forceinline__ bf16x8 pack8(float a0,float a1,float a2,float a3,
                                        float a4,float a5,float a6,float a7){
    uint4 r;
    r.x = (u32)f2b(a0) | ((u32)f2b(a1) << 16);
    r.y = (u32)f2b(a2) | ((u32)f2b(a3) << 16);
    r.z = (u32)f2b(a4) | ((u32)f2b(a5) << 16);
    r.w = (u32)f2b(a6) | ((u32)f2b(a7) << 16);
    return __builtin_bit_cast(bf16x8, r);
}
__device__ __forceinline__ bf16x8 ldg8(const u16* p){
    return __builtin_bit_cast(bf16x8, *(const uint4*)p);
}
// swizzled LDS bf16 tile: slot(row, granule g) at row*128 + ((g^(row&7))<<3)
__device__ __forceinline__ bf16x8 ldA(const u16* Xs, int row, int gk){
    return __builtin_bit_cast(bf16x8,
        *(const uint4*)(&Xs[row*128 + ((gk ^ (row & 7)) << 3)]));
}
__device__ __forceinline__ int swz_slot(int row, int col){
    return row*128 + (((col >> 3) ^ (row & 7)) << 3) + (col & 7);
}

// ---------------- K1: weight convert fp32 -> bf16 ----------------
__global__ __launch_bounds__(1024) void k_wcvt(
    const float* __restrict__ wd, const float* __restrict__ we,
    const float* __restrict__ wp, const float* __restrict__ wih,
    const float* __restrict__ whh,
    u16* __restrict__ wdb, u16* __restrict__ web, u16* __restrict__ wpb,
    u16* __restrict__ wib, u16* __restrict__ whb)
{
    int i = blockIdx.x*1024 + threadIdx.x;    // 0..18431
    int e = i*8;
    const float* src; u16* dst; int off;
    if      (e < 16384) { src = wd;  dst = wdb; off = e; }
    else if (e < 32768) { src = we;  dst = web; off = e - 16384; }
    else if (e < 49152) { src = wp;  dst = wpb; off = e - 32768; }
    else if (e < 98304) { src = wih; dst = wib; off = e - 49152; }
    else                { src = whh; dst = whb; off = e - 98304; }
    float4 a = *(const float4*)(src + off);
    float4 b = *(const float4*)(src + off + 4);
    uint4 r;
    r.x = (u32)f2b(a.x) | ((u32)f2b(a.y) << 16);
    r.y = (u32)f2b(a.z) | ((u32)f2b(a.w) << 16);
    r.z = (u32)f2b(b.x) | ((u32)f2b(b.y) << 16);
    r.w = (u32)f2b(b.z) | ((u32)f2b(b.w) << 16);
    *(uint4*)(dst + off) = r;
}

// ---------------- K2: per-batch mega kernel (fused gather+partials) ----------------
// grid 256, 512 thr (8 waves x 16-col strips)
__global__ __launch_bounds__(512,2) void k_mega(
    const int* __restrict__ pair, const int* __restrict__ relset,
    const int* __restrict__ path,
    const float* __restrict__ emb, const float* __restrict__ eu,
    const float* __restrict__ eub,
    const u16* __restrict__ wdb, const float* __restrict__ bd,
    const u16* __restrict__ web, const float* __restrict__ be,
    const u16* __restrict__ wpb, const float* __restrict__ bpv_,
    const u16* __restrict__ wib, const u16* __restrict__ whb,
    const float* __restrict__ bih, const float* __restrict__ bhh,
    float* __restrict__ out)
{
    __shared__ u16   Xs[GROWS*128];          // 48 KB rel tile (swizzled bf16)
    __shared__ u16   X2[GROWS*128];          // 48 KB cost-adjusted tile
    __shared__ u16   Hs[64*128];             // 16 KB GRU state
    __shared__ float pdh[GROWS], pdt[GROWS], pdu[GROWS], pnn[GROWS];
    __shared__ float sdS[GROWS], seS[GROWS];
    __shared__ float s_hts, s_hi, s_ti;
    __shared__ float s_part[8];

    const int b    = blockIdx.x;
    const int tid  = threadIdx.x;
    const int wave = tid >> 6, lane = tid & 63;
    const int lrow = lane & 15, lk8 = lane >> 4;
    const int col  = wave*16 + lrow;
    const float eb = eub[0];

    // ---- P0: D/E weight fragments (bf16, pre-converted) ----
    bf16x8 fD[4], fE[4];
    #pragma unroll
    for (int ks = 0; ks < 4; ++ks) {
        const int gk = ks*4 + lk8;
        fD[ks] = ldg8(wdb + col*128 + gk*8);
        fE[ks] = ldg8(web + col*128 + gk*8);
    }
    const int ph = pair[2*b], ptl = pair[2*b+1];

    // ---- P1: pair stats (wave 0), relset denominator, fused gather+partials ----
    if (wave == 0) {
        float2 hv2 = *(const float2*)(emb + (size_t)ph*128 + 2*lane);
        float2 tv2 = *(const float2*)(emb + (size_t)ptl*128 + 2*lane);
        float dht = hv2.x*tv2.x + hv2.y*tv2.y;
        float dhh = hv2.x*hv2.x + hv2.y*hv2.y;
        float dtt = tv2.x*tv2.x + tv2.y*tv2.y;
        #pragma unroll
        for (int o = 32; o > 0; o >>= 1) {
            dht += __shfl_xor(dht, o);
            dhh += __shfl_xor(dhh, o);
            dtt += __shfl_xor(dtt, o);
        }
        if (lane == 0) {
            float hn = 1.f / fmaxf(sqrtf(dhh), EPS_);
            float tn = 1.f / fmaxf(sqrtf(dtt), EPS_);
            s_hts = dht*hn*tn;
            s_hi  = hn;
            s_ti  = tn;
        }
    }
    {
        // softmax denominator: 4 relset rows per wave
        float2 uv2 = *(const float2*)(eu + 2*lane);
        float accs = 0.f;
        #pragma unroll
        for (int k = 0; k < 4; ++k) {
            const int ri = relset[b*R_ + wave*4 + k];
            float2 ev = *(const float2*)(emb + (size_t)ri*128 + 2*lane);
            float du = ev.x*uv2.x + ev.y*uv2.y;
            #pragma unroll
            for (int o = 32; o > 0; o >>= 1) du += __shfl_xor(du, o);
            accs += __expf(du + eb);
        }
        if (lane == 0) s_part[wave] = accs;
    }
    {
        // fused gather + per-row partials:
        // granule position g = tid&15 is iteration-invariant; row r = i*32 + (tid>>4)
        const int l16 = tid & 15;
        const int rg  = tid >> 4;            // 0..31
        float hq[8], tq[8], uq[8];
        {
            const float* hpq = emb + (size_t)ph*128  + l16*8;
            const float* tpq = emb + (size_t)ptl*128 + l16*8;
            const float* upq = eu + l16*8;
            float4 a0 = *(const float4*)hpq, a1 = *(const float4*)(hpq+4);
            float4 b0 = *(const float4*)tpq, b1 = *(const float4*)(tpq+4);
            float4 c0 = *(const float4*)upq, c1 = *(const float4*)(upq+4);
            hq[0]=a0.x;hq[1]=a0.y;hq[2]=a0.z;hq[3]=a0.w;hq[4]=a1.x;hq[5]=a1.y;hq[6]=a1.z;hq[7]=a1.w;
            tq[0]=b0.x;tq[1]=b0.y;tq[2]=b0.z;tq[3]=b0.w;tq[4]=b1.x;tq[5]=b1.y;tq[6]=b1.z;tq[7]=b1.w;
            uq[0]=c0.x;uq[1]=c0.y;uq[2]=c0.z;uq[3]=c0.w;uq[4]=c1.x;uq[5]=c1.y;uq[6]=c1.z;uq[7]=c1.w;
        }
        #pragma unroll
        for (int i = 0; i < 6; ++i) {
            const int r = i*32 + rg;
            const int pidx = path[b*GROWS + r];          // 16-lane broadcast read
            const float* sp = emb + (size_t)pidx*128 + l16*8;
            float4 f0 = *(const float4*)sp;
            float4 f1 = *(const float4*)(sp + 4);
            float v[8] = {f0.x,f0.y,f0.z,f0.w, f1.x,f1.y,f1.z,f1.w};
            // fp32 partials for sim/e_score (matches reference numerics)
            float dh=0.f, dt=0.f, du=0.f, nn=0.f;
            #pragma unroll
            for (int j = 0; j < 8; ++j) {
                dh = fmaf(v[j], hq[j], dh);
                dt = fmaf(v[j], tq[j], dt);
                du = fmaf(v[j], uq[j], du);
                nn = fmaf(v[j], v[j], nn);
            }
            #pragma unroll
            for (int o = 8; o > 0; o >>= 1) {
                dh += __shfl_xor(dh, o);
                dt += __shfl_xor(dt, o);
                du += __shfl_xor(du, o);
                nn += __shfl_xor(nn, o);
            }
            if (l16 == 0) { pdh[r]=dh; pdt[r]=dt; pdu[r]=du; pnn[r]=nn; }
            // convert & store swizzled bf16
            bf16x8 bv = pack8(v[0],v[1],v[2],v[3],v[4],v[5],v[6],v[7]);
            *(uint4*)(&Xs[r*128 + ((l16 ^ (r & 7)) << 3)]) = __builtin_bit_cast(uint4, bv);
        }
    }
    __syncthreads();

    // ---- P3: sd/se scalars (thread p = tid < 64) ----
    if (tid < 64) {
        float is = 0.f;
        #pragma unroll
        for (int w = 0; w < 8; ++w) is += s_part[w];
        is = 1.f/is;
        const float hi = s_hi, ti = s_ti, ht = s_hts;
        const int r1 = 3*tid, r2 = r1+1, r3 = r1+2;
        float n1i = 1.f / fmaxf(sqrtf(pnn[r1]), EPS_);
        float n2i = 1.f / fmaxf(sqrtf(pnn[r2]), EPS_);
        float se1 = 0.5f*(pdh[r1]*hi + pdt[r1]*ti)*n1i;
        float se2 = 0.5f*(pdh[r2]*hi + pdt[r2]*ti)*n2i;
        sdS[r1] = (1.f - 0.5f*(ht  + se1))*0.5f;
        sdS[r2] = (1.f - 0.5f*(se1 + se2))*0.5f;
        sdS[r3] = (1.f - 0.5f*(ht  + se2))*0.5f;
        seS[r1] = __expf(pdu[r1] + eb)*is;
        seS[r2] = __expf(pdu[r2] + eb)*is;
        seS[r3] = __expf(pdu[r3] + eb)*is;
    }
    __syncthreads();

    // ---- P4a: STREAMING D/E GEMM + cost epilogue -> X2 (no mid barriers) ----
    {
        const float bde = bd[col] + be[col];
        #pragma unroll 2
        for (int mt = 0; mt < 12; ++mt) {
            f32x4 aD = (f32x4){0,0,0,0}, aE = (f32x4){0,0,0,0};
            #pragma unroll
            for (int ks = 0; ks < 4; ++ks) {
                const int gk = ks*4 + lk8;
                bf16x8 a = ldA(Xs, mt*16 + lrow, gk);
                aD = __builtin_amdgcn_mfma_f32_16x16x32_bf16(a, fD[ks], aD, 0,0,0);
                aE = __builtin_amdgcn_mfma_f32_16x16x32_bf16(a, fE[ks], aE, 0,0,0);
            }
            #pragma unroll
            for (int rr = 0; rr < 4; ++rr) {
                const int row = mt*16 + lk8*4 + rr;
                const int sl  = swz_slot(row, col);
                float relv = b2f(Xs[sl]);
                float c = sdS[row]*aD[rr] + seS[row]*aE[rr] + bde;
                X2[sl] = f2b(relv - 1e-3f*fmaxf(c, 0.f));
            }
        }
    }
    __syncthreads();   // X2 complete

    // ---- P4b: STREAMING P GEMM -> rel_in back into Xs ----
    {
        bf16x8 fP[4];
        #pragma unroll
        for (int ks = 0; ks < 4; ++ks)
            fP[ks] = ldg8(wpb + col*128 + (ks*4 + lk8)*8);
        const float bpv = bpv_[col];
        #pragma unroll 2
        for (int mt = 0; mt < 12; ++mt) {
            f32x4 aP = (f32x4){0,0,0,0};
            #pragma unroll
            for (int ks = 0; ks < 4; ++ks) {
                const int gk = ks*4 + lk8;
                bf16x8 a = ldA(X2, mt*16 + lrow, gk);
                aP = __builtin_amdgcn_mfma_f32_16x16x32_bf16(a, fP[ks], aP, 0,0,0);
            }
            #pragma unroll
            for (int rr = 0; rr < 4; ++rr) {
                const int row = mt*16 + lk8*4 + rr;
                Xs[swz_slot(row, col)] = f2b(aP[rr] + bpv);
            }
        }
    }

    // ---- GRU x-side weight fragments: issue before barrier (latency hidden) ----
    bf16x8 wR[4], wZ[4], wI[4];
    #pragma unroll
    for (int ks = 0; ks < 4; ++ks) {
        const int gk = ks*4 + lk8;
        wR[ks] = ldg8(wib +           col*128 + gk*8);
        wZ[ks] = ldg8(wib + 16384   + col*128 + gk*8);
        wI[ks] = ldg8(wib + 2*16384 + col*128 + gk*8);
    }
    const float brv = bih[col]       + bhh[col];
    const float bzv = bih[128 + col] + bhh[128 + col];
    const float biN = bih[256 + col];
    const float bhN = bhh[256 + col];
    __syncthreads();   // Xs = rel_in complete

    // ---- P5: GRU over 64 bp rows; h-side weights reloaded per t (L2-hot bf16) ----
    float hreg[4][4];
    f32x4 aR[4], aZ[4], aI[4], aH[4];

    // t = 0 (h = 0)
    #pragma unroll
    for (int m = 0; m < 4; ++m) { aR[m]=(f32x4){0,0,0,0}; aZ[m]=(f32x4){0,0,0,0}; aI[m]=(f32x4){0,0,0,0}; }
    #pragma unroll
    for (int ks = 0; ks < 4; ++ks) {
        const int gk = ks*4 + lk8;
        #pragma unroll
        for (int mt = 0; mt < 4; ++mt) {
            bf16x8 ax = ldA(Xs, 3*(mt*16 + lrow) + 0, gk);
            aR[mt] = __builtin_amdgcn_mfma_f32_16x16x32_bf16(ax, wR[ks], aR[mt], 0,0,0);
            aZ[mt] = __builtin_amdgcn_mfma_f32_16x16x32_bf16(ax, wZ[ks], aZ[mt], 0,0,0);
            aI[mt] = __builtin_amdgcn_mfma_f32_16x16x32_bf16(ax, wI[ks], aI[mt], 0,0,0);
        }
    }
    #pragma unroll
    for (int mt = 0; mt < 4; ++mt)
        #pragma unroll
        for (int rr = 0; rr < 4; ++rr) {
            const int row = mt*16 + lk8*4 + rr;
            float rv = sigm_f(aR[mt][rr] + brv);
            float zv = sigm_f(aZ[mt][rr] + bzv);
            float nn = tanh_f(aI[mt][rr] + biN + rv*bhN);
            float h2 = (1.f - zv)*nn;
            hreg[mt][rr] = h2;
            Hs[swz_slot(row, col)] = f2b(h2);
        }
    __syncthreads();

    // t = 1, 2
    #pragma unroll
    for (int t = 1; t < 3; ++t) {
        #pragma unroll
        for (int m = 0; m < 4; ++m) { aR[m]=(f32x4){0,0,0,0}; aZ[m]=(f32x4){0,0,0,0}; aI[m]=(f32x4){0,0,0,0}; aH[m]=(f32x4){0,0,0,0}; }
        #pragma unroll
        for (int ks = 0; ks < 4; ++ks) {
            const int gk = ks*4 + lk8;
            bf16x8 vRk = ldg8(whb +           col*128 + gk*8);
            bf16x8 vZk = ldg8(whb + 16384   + col*128 + gk*8);
            bf16x8 vHk = ldg8(whb + 2*16384 + col*128 + gk*8);
            #pragma unroll
            for (int mt = 0; mt < 4; ++mt) {
                bf16x8 ax = ldA(Xs, 3*(mt*16 + lrow) + t, gk);
                bf16x8 ah = ldA(Hs, mt*16 + lrow, gk);
                aR[mt] = __builtin_amdgcn_mfma_f32_16x16x32_bf16(ax, wR[ks], aR[mt], 0,0,0);
                aZ[mt] = __builtin_amdgcn_mfma_f32_16x16x32_bf16(ax, wZ[ks], aZ[mt], 0,0,0);
                aI[mt] = __builtin_amdgcn_mfma_f32_16x16x32_bf16(ax, wI[ks], aI[mt], 0,0,0);
                aR[mt] = __builtin_amdgcn_mfma_f32_16x16x32_bf16(ah, vRk, aR[mt], 0,0,0);
                aZ[mt] = __builtin_amdgcn_mfma_f32_16x16x32_bf16(ah, vZk, aZ[mt], 0,0,0);
                aH[mt] = __builtin_amdgcn_mfma_f32_16x16x32_bf16(ah, vHk, aH[mt], 0,0,0);
            }
        }
        __syncthreads();              // all Hs reads of this step complete
        if (t < 2) {
            #pragma unroll
            for (int mt = 0; mt < 4; ++mt)
                #pragma unroll
                for (int rr = 0; rr < 4; ++rr) {
                    const int row = mt*16 + lk8*4 + rr;
                    float rv = sigm_f(aR[mt][rr] + brv);
                    float zv = sigm_f(aZ[mt][rr] + bzv);
                    float hn = aH[mt][rr] + bhN;
                    float nn = tanh_f(aI[mt][rr] + biN + rv*hn);
                    float h2 = (1.f - zv)*nn + zv*hreg[mt][rr];
                    hreg[mt][rr] = h2;
                    Hs[swz_slot(row, col)] = f2b(h2);
                }
            __syncthreads();
        } else {
            const int bp0 = b*64;
            #pragma unroll
            for (int mt = 0; mt < 4; ++mt)
                #pragma unroll
                for (int rr = 0; rr < 4; ++rr) {
                    const int row = mt*16 + lk8*4 + rr;
                    float rv = sigm_f(aR[mt][rr] + brv);
                    float zv = sigm_f(aZ[mt][rr] + bzv);
                    float hn = aH[mt][rr] + bhN;
                    float nn = tanh_f(aI[mt][rr] + biN + rv*hn);
                    float h2 = (1.f - zv)*nn + zv*hreg[mt][rr];
                    out[(size_t)(bp0 + row)*128 + col] = h2;
                }
        }
    }
}

extern "C" void kernel_launch(void* const* d_in, const int* in_sizes, int n_in,
                              void* d_out, int out_size, void* d_ws, size_t ws_size,
                              hipStream_t stream)
{
    const int*   path   = (const int*)d_in[0];
    const int*   pair   = (const int*)d_in[1];
    const int*   relset = (const int*)d_in[2];
    const float* emb    = (const float*)d_in[3];
    const float* wd     = (const float*)d_in[4];
    const float* bd     = (const float*)d_in[5];
    const float* we     = (const float*)d_in[6];
    const float* be     = (const float*)d_in[7];
    const float* wp     = (const float*)d_in[8];
    const float* bp     = (const float*)d_in[9];
    const float* eu     = (const float*)d_in[10];
    const float* eub    = (const float*)d_in[11];
    const float* wih    = (const float*)d_in[12];
    const float* whh    = (const float*)d_in[13];
    const float* bih    = (const float*)d_in[14];
    const float* bhh    = (const float*)d_in[15];
    float* out = (float*)d_out;
    float* ws  = (float*)d_ws;

    // workspace: only bf16 weights (~288 KB)
    u16* wdb = (u16*)ws;               // 16384 u16
    u16* web = wdb + 16384;
    u16* wpb = web + 16384;
    u16* wib = wpb + 16384;            // 49152 u16
    u16* whb = wib + 49152;            // ends at 147456 u16 = 288 KB

    k_wcvt<<<18, 1024, 0, stream>>>(wd, we, wp, wih, whh, wdb, web, wpb, wib, whb);
    k_mega<<<B_, 512, 0, stream>>>(pair, relset, path, emb, eu, eub,
                                   wdb, bd, web, be, wpb, bp,
                                   wib, whb, bih, bhh, out);
}

// Round 18
// 42.702 us; speedup vs baseline: 1.6201x; 1.0393x over previous
//
#include <hip/hip_runtime.h>
#include <cmath>

#define D_ 128
#define B_ 256
#define P_ 64
#define R_ 32
#define GROWS 192        /* rel rows per batch block */
#define EPS_ 1e-8f

typedef unsigned short u16;
typedef unsigned int   u32;
using bf16x8 = __attribute__((ext_vector_type(8))) __bf16;
using f32x4  = __attribute__((ext_vector_type(4))) float;

__device__ __forceinline__ float sigm_f(float x){ return 1.0f/(1.0f + __expf(-x)); }
__device__ __forceinline__ float tanh_f(float x){
    float e = __expf(2.0f*x);
    return 1.0f - 2.0f/(e + 1.0f);
}

__device__ __forceinline__ u16 f2b(float f){         // fp32 -> bf16 RNE
    u32 u = __builtin_bit_cast(u32, f);
    u += 0x7fffu + ((u >> 16) & 1u);
    return (u16)(u >> 16);
}
__device__ __forceinline__ float b2f(u16 s){
    return __builtin_bit_cast(float, ((u32)s) << 16);
}
__device__ __forceinline__ bf16x8 pack8(float a0,float a1,float a2,float a3,
                                        float a4,float a5,float a6,float a7){
    uint4 r;
    r.x = (u32)f2b(a0) | ((u32)f2b(a1) << 16);
    r.y = (u32)f2b(a2) | ((u32)f2b(a3) << 16);
    r.z = (u32)f2b(a4) | ((u32)f2b(a5) << 16);
    r.w = (u32)f2b(a6) | ((u32)f2b(a7) << 16);
    return __builtin_bit_cast(bf16x8, r);
}
__device__ __forceinline__ bf16x8 ldg8(const u16* p){
    return __builtin_bit_cast(bf16x8, *(const uint4*)p);
}
// swizzled LDS bf16 tile: slot(row, granule g) at row*128 + ((g^(row&7))<<3)
__device__ __forceinline__ bf16x8 ldA(const u16* Xs, int row, int gk){
    return __builtin_bit_cast(bf16x8,
        *(const uint4*)(&Xs[row*128 + ((gk ^ (row & 7)) << 3)]));
}
__device__ __forceinline__ int swz_slot(int row, int col){
    return row*128 + (((col >> 3) ^ (row & 7)) << 3) + (col & 7);
}

// ---------------- K1: weight convert fp32 -> bf16 ----------------
__global__ __launch_bounds__(1024) void k_wcvt(
    const float* __restrict__ wd, const float* __restrict__ we,
    const float* __restrict__ wp, const float* __restrict__ wih,
    const float* __restrict__ whh,
    u16* __restrict__ wdb, u16* __restrict__ web, u16* __restrict__ wpb,
    u16* __restrict__ wib, u16* __restrict__ whb)
{
    int i = blockIdx.x*1024 + threadIdx.x;    // 0..18431
    int e = i*8;
    const float* src; u16* dst; int off;
    if      (e < 16384) { src = wd;  dst = wdb; off = e; }
    else if (e < 32768) { src = we;  dst = web; off = e - 16384; }
    else if (e < 49152) { src = wp;  dst = wpb; off = e - 32768; }
    else if (e < 98304) { src = wih; dst = wib; off = e - 49152; }
    else                { src = whh; dst = whb; off = e - 98304; }
    float4 a = *(const float4*)(src + off);
    float4 b = *(const float4*)(src + off + 4);
    uint4 r;
    r.x = (u32)f2b(a.x) | ((u32)f2b(a.y) << 16);
    r.y = (u32)f2b(a.z) | ((u32)f2b(a.w) << 16);
    r.z = (u32)f2b(b.x) | ((u32)f2b(b.y) << 16);
    r.w = (u32)f2b(b.z) | ((u32)f2b(b.w) << 16);
    *(uint4*)(dst + off) = r;
}

// ---------------- K2: per-batch mega kernel (burst-MLP gather) ----------------
// grid 256, 512 thr (8 waves x 16-col strips)
__global__ __launch_bounds__(512,2) void k_mega(
    const int* __restrict__ pair, const int* __restrict__ relset,
    const int* __restrict__ path,
    const float* __restrict__ emb, const float* __restrict__ eu,
    const float* __restrict__ eub,
    const u16* __restrict__ wdb, const float* __restrict__ bd,
    const u16* __restrict__ web, const float* __restrict__ be,
    const u16* __restrict__ wpb, const float* __restrict__ bpv_,
    const u16* __restrict__ wib, const u16* __restrict__ whb,
    const float* __restrict__ bih, const float* __restrict__ bhh,
    float* __restrict__ out)
{
    __shared__ u16   Xs[GROWS*128];          // 48 KB rel tile (swizzled bf16)
    __shared__ u16   X2[GROWS*128];          // 48 KB cost-adjusted tile
    __shared__ u16   Hs[64*128];             // 16 KB GRU state
    __shared__ float pdh[GROWS], pdt[GROWS], pdu[GROWS], pnn[GROWS];
    __shared__ float sdS[GROWS], seS[GROWS];
    __shared__ float s_hts, s_hi, s_ti;
    __shared__ float s_part[8];

    const int b    = blockIdx.x;
    const int tid  = threadIdx.x;
    const int wave = tid >> 6, lane = tid & 63;
    const int lrow = lane & 15, lk8 = lane >> 4;
    const int col  = wave*16 + lrow;
    const float eb = eub[0];
    const int ph = pair[2*b], ptl = pair[2*b+1];

    // ---- P1: burst-issue ALL gather loads, then stats/denominator, then drain ----
    {
        const int l16 = tid & 15;
        const int rg  = tid >> 5;            // 0..15  (32-lane grouping unused)
        const int grp = tid >> 4;            // 0..31  16-lane group id
        // 1) all 6 path indices (independent broadcast loads)
        int pidx[6];
        #pragma unroll
        for (int i = 0; i < 6; ++i) pidx[i] = path[b*GROWS + i*32 + grp];
        // 2) burst-issue all 12 row float4 loads into registers
        float4 rv0[6], rv1[6];
        #pragma unroll
        for (int i = 0; i < 6; ++i) {
            const float* sp = emb + (size_t)pidx[i]*128 + l16*8;
            rv0[i] = *(const float4*)sp;
            rv1[i] = *(const float4*)(sp + 4);
        }
        // 3) query slices (h/t/u) — independent, overlap with row loads
        float hq[8], tq[8], uq[8];
        {
            const float* hpq = emb + (size_t)ph*128  + l16*8;
            const float* tpq = emb + (size_t)ptl*128 + l16*8;
            const float* upq = eu + l16*8;
            float4 a0 = *(const float4*)hpq, a1 = *(const float4*)(hpq+4);
            float4 b0 = *(const float4*)tpq, b1 = *(const float4*)(tpq+4);
            float4 c0 = *(const float4*)upq, c1 = *(const float4*)(upq+4);
            hq[0]=a0.x;hq[1]=a0.y;hq[2]=a0.z;hq[3]=a0.w;hq[4]=a1.x;hq[5]=a1.y;hq[6]=a1.z;hq[7]=a1.w;
            tq[0]=b0.x;tq[1]=b0.y;tq[2]=b0.z;tq[3]=b0.w;tq[4]=b1.x;tq[5]=b1.y;tq[6]=b1.z;tq[7]=b1.w;
            uq[0]=c0.x;uq[1]=c0.y;uq[2]=c0.z;uq[3]=c0.w;uq[4]=c1.x;uq[5]=c1.y;uq[6]=c1.z;uq[7]=c1.w;
        }
        // 4) pair stats (wave 0) — loads overlap the gather flight
        if (wave == 0) {
            float2 hv2 = *(const float2*)(emb + (size_t)ph*128 + 2*lane);
            float2 tv2 = *(const float2*)(emb + (size_t)ptl*128 + 2*lane);
            float dht = hv2.x*tv2.x + hv2.y*tv2.y;
            float dhh = hv2.x*hv2.x + hv2.y*hv2.y;
            float dtt = tv2.x*tv2.x + tv2.y*tv2.y;
            #pragma unroll
            for (int o = 32; o > 0; o >>= 1) {
                dht += __shfl_xor(dht, o);
                dhh += __shfl_xor(dhh, o);
                dtt += __shfl_xor(dtt, o);
            }
            if (lane == 0) {
                float hn = 1.f / fmaxf(sqrtf(dhh), EPS_);
                float tn = 1.f / fmaxf(sqrtf(dtt), EPS_);
                s_hts = dht*hn*tn;
                s_hi  = hn;
                s_ti  = tn;
            }
        }
        // 5) softmax denominator: burst 4 index loads then 4 row loads
        {
            float2 uv2 = *(const float2*)(eu + 2*lane);
            int ri[4];
            #pragma unroll
            for (int k = 0; k < 4; ++k) ri[k] = relset[b*R_ + wave*4 + k];
            float2 ev[4];
            #pragma unroll
            for (int k = 0; k < 4; ++k)
                ev[k] = *(const float2*)(emb + (size_t)ri[k]*128 + 2*lane);
            float accs = 0.f;
            #pragma unroll
            for (int k = 0; k < 4; ++k) {
                float du = ev[k].x*uv2.x + ev[k].y*uv2.y;
                #pragma unroll
                for (int o = 32; o > 0; o >>= 1) du += __shfl_xor(du, o);
                accs += __expf(du + eb);
            }
            if (lane == 0) s_part[wave] = accs;
        }
        // 6) drain gather rows: partials + reduce + swizzled bf16 store
        #pragma unroll
        for (int i = 0; i < 6; ++i) {
            const int r = i*32 + grp;
            float v[8] = {rv0[i].x,rv0[i].y,rv0[i].z,rv0[i].w,
                          rv1[i].x,rv1[i].y,rv1[i].z,rv1[i].w};
            float dh=0.f, dt=0.f, du=0.f, nn=0.f;
            #pragma unroll
            for (int j = 0; j < 8; ++j) {
                dh = fmaf(v[j], hq[j], dh);
                dt = fmaf(v[j], tq[j], dt);
                du = fmaf(v[j], uq[j], du);
                nn = fmaf(v[j], v[j], nn);
            }
            #pragma unroll
            for (int o = 8; o > 0; o >>= 1) {
                dh += __shfl_xor(dh, o);
                dt += __shfl_xor(dt, o);
                du += __shfl_xor(du, o);
                nn += __shfl_xor(nn, o);
            }
            if (l16 == 0) { pdh[r]=dh; pdt[r]=dt; pdu[r]=du; pnn[r]=nn; }
            bf16x8 bv = pack8(v[0],v[1],v[2],v[3],v[4],v[5],v[6],v[7]);
            *(uint4*)(&Xs[r*128 + ((l16 ^ (r & 7)) << 3)]) = __builtin_bit_cast(uint4, bv);
        }
        (void)rg;
    }

    // ---- D/E weight fragments (bf16, pre-converted) — after the burst ----
    bf16x8 fD[4], fE[4];
    #pragma unroll
    for (int ks = 0; ks < 4; ++ks) {
        const int gk = ks*4 + lk8;
        fD[ks] = ldg8(wdb + col*128 + gk*8);
        fE[ks] = ldg8(web + col*128 + gk*8);
    }
    __syncthreads();

    // ---- P3: sd/se scalars (thread p = tid < 64) ----
    if (tid < 64) {
        float is = 0.f;
        #pragma unroll
        for (int w = 0; w < 8; ++w) is += s_part[w];
        is = 1.f/is;
        const float hi = s_hi, ti = s_ti, ht = s_hts;
        const int r1 = 3*tid, r2 = r1+1, r3 = r1+2;
        float n1i = 1.f / fmaxf(sqrtf(pnn[r1]), EPS_);
        float n2i = 1.f / fmaxf(sqrtf(pnn[r2]), EPS_);
        float se1 = 0.5f*(pdh[r1]*hi + pdt[r1]*ti)*n1i;
        float se2 = 0.5f*(pdh[r2]*hi + pdt[r2]*ti)*n2i;
        sdS[r1] = (1.f - 0.5f*(ht  + se1))*0.5f;
        sdS[r2] = (1.f - 0.5f*(se1 + se2))*0.5f;
        sdS[r3] = (1.f - 0.5f*(ht  + se2))*0.5f;
        seS[r1] = __expf(pdu[r1] + eb)*is;
        seS[r2] = __expf(pdu[r2] + eb)*is;
        seS[r3] = __expf(pdu[r3] + eb)*is;
    }
    __syncthreads();

    // ---- P4a: STREAMING D/E GEMM + cost epilogue -> X2 (no mid barriers) ----
    {
        const float bde = bd[col] + be[col];
        #pragma unroll 2
        for (int mt = 0; mt < 12; ++mt) {
            f32x4 aD = (f32x4){0,0,0,0}, aE = (f32x4){0,0,0,0};
            #pragma unroll
            for (int ks = 0; ks < 4; ++ks) {
                const int gk = ks*4 + lk8;
                bf16x8 a = ldA(Xs, mt*16 + lrow, gk);
                aD = __builtin_amdgcn_mfma_f32_16x16x32_bf16(a, fD[ks], aD, 0,0,0);
                aE = __builtin_amdgcn_mfma_f32_16x16x32_bf16(a, fE[ks], aE, 0,0,0);
            }
            #pragma unroll
            for (int rr = 0; rr < 4; ++rr) {
                const int row = mt*16 + lk8*4 + rr;
                const int sl  = swz_slot(row, col);
                float relv = b2f(Xs[sl]);
                float c = sdS[row]*aD[rr] + seS[row]*aE[rr] + bde;
                X2[sl] = f2b(relv - 1e-3f*fmaxf(c, 0.f));
            }
        }
    }
    __syncthreads();   // X2 complete

    // ---- P4b: STREAMING P GEMM -> rel_in back into Xs ----
    {
        bf16x8 fP[4];
        #pragma unroll
        for (int ks = 0; ks < 4; ++ks)
            fP[ks] = ldg8(wpb + col*128 + (ks*4 + lk8)*8);
        const float bpv = bpv_[col];
        #pragma unroll 2
        for (int mt = 0; mt < 12; ++mt) {
            f32x4 aP = (f32x4){0,0,0,0};
            #pragma unroll
            for (int ks = 0; ks < 4; ++ks) {
                const int gk = ks*4 + lk8;
                bf16x8 a = ldA(X2, mt*16 + lrow, gk);
                aP = __builtin_amdgcn_mfma_f32_16x16x32_bf16(a, fP[ks], aP, 0,0,0);
            }
            #pragma unroll
            for (int rr = 0; rr < 4; ++rr) {
                const int row = mt*16 + lk8*4 + rr;
                Xs[swz_slot(row, col)] = f2b(aP[rr] + bpv);
            }
        }
    }

    // ---- GRU x-side weight fragments: issue before barrier (latency hidden) ----
    bf16x8 wR[4], wZ[4], wI[4];
    #pragma unroll
    for (int ks = 0; ks < 4; ++ks) {
        const int gk = ks*4 + lk8;
        wR[ks] = ldg8(wib +           col*128 + gk*8);
        wZ[ks] = ldg8(wib + 16384   + col*128 + gk*8);
        wI[ks] = ldg8(wib + 2*16384 + col*128 + gk*8);
    }
    const float brv = bih[col]       + bhh[col];
    const float bzv = bih[128 + col] + bhh[128 + col];
    const float biN = bih[256 + col];
    const float bhN = bhh[256 + col];
    __syncthreads();   // Xs = rel_in complete

    // ---- P5: GRU over 64 bp rows; h-side weights reloaded per t (L2-hot bf16) ----
    float hreg[4][4];
    f32x4 aR[4], aZ[4], aI[4], aH[4];

    // t = 0 (h = 0)
    #pragma unroll
    for (int m = 0; m < 4; ++m) { aR[m]=(f32x4){0,0,0,0}; aZ[m]=(f32x4){0,0,0,0}; aI[m]=(f32x4){0,0,0,0}; }
    #pragma unroll
    for (int ks = 0; ks < 4; ++ks) {
        const int gk = ks*4 + lk8;
        #pragma unroll
        for (int mt = 0; mt < 4; ++mt) {
            bf16x8 ax = ldA(Xs, 3*(mt*16 + lrow) + 0, gk);
            aR[mt] = __builtin_amdgcn_mfma_f32_16x16x32_bf16(ax, wR[ks], aR[mt], 0,0,0);
            aZ[mt] = __builtin_amdgcn_mfma_f32_16x16x32_bf16(ax, wZ[ks], aZ[mt], 0,0,0);
            aI[mt] = __builtin_amdgcn_mfma_f32_16x16x32_bf16(ax, wI[ks], aI[mt], 0,0,0);
        }
    }
    #pragma unroll
    for (int mt = 0; mt < 4; ++mt)
        #pragma unroll
        for (int rr = 0; rr < 4; ++rr) {
            const int row = mt*16 + lk8*4 + rr;
            float rv = sigm_f(aR[mt][rr] + brv);
            float zv = sigm_f(aZ[mt][rr] + bzv);
            float nn = tanh_f(aI[mt][rr] + biN + rv*bhN);
            float h2 = (1.f - zv)*nn;
            hreg[mt][rr] = h2;
            Hs[swz_slot(row, col)] = f2b(h2);
        }
    __syncthreads();

    // t = 1, 2
    #pragma unroll
    for (int t = 1; t < 3; ++t) {
        #pragma unroll
        for (int m = 0; m < 4; ++m) { aR[m]=(f32x4){0,0,0,0}; aZ[m]=(f32x4){0,0,0,0}; aI[m]=(f32x4){0,0,0,0}; aH[m]=(f32x4){0,0,0,0}; }
        #pragma unroll
        for (int ks = 0; ks < 4; ++ks) {
            const int gk = ks*4 + lk8;
            bf16x8 vRk = ldg8(whb +           col*128 + gk*8);
            bf16x8 vZk = ldg8(whb + 16384   + col*128 + gk*8);
            bf16x8 vHk = ldg8(whb + 2*16384 + col*128 + gk*8);
            #pragma unroll
            for (int mt = 0; mt < 4; ++mt) {
                bf16x8 ax = ldA(Xs, 3*(mt*16 + lrow) + t, gk);
                bf16x8 ah = ldA(Hs, mt*16 + lrow, gk);
                aR[mt] = __builtin_amdgcn_mfma_f32_16x16x32_bf16(ax, wR[ks], aR[mt], 0,0,0);
                aZ[mt] = __builtin_amdgcn_mfma_f32_16x16x32_bf16(ax, wZ[ks], aZ[mt], 0,0,0);
                aI[mt] = __builtin_amdgcn_mfma_f32_16x16x32_bf16(ax, wI[ks], aI[mt], 0,0,0);
                aR[mt] = __builtin_amdgcn_mfma_f32_16x16x32_bf16(ah, vRk, aR[mt], 0,0,0);
                aZ[mt] = __builtin_amdgcn_mfma_f32_16x16x32_bf16(ah, vZk, aZ[mt], 0,0,0);
                aH[mt] = __builtin_amdgcn_mfma_f32_16x16x32_bf16(ah, vHk, aH[mt], 0,0,0);
            }
        }
        __syncthreads();              // all Hs reads of this step complete
        if (t < 2) {
            #pragma unroll
            for (int mt = 0; mt < 4; ++mt)
                #pragma unroll
                for (int rr = 0; rr < 4; ++rr) {
                    const int row = mt*16 + lk8*4 + rr;
                    float rv = sigm_f(aR[mt][rr] + brv);
                    float zv = sigm_f(aZ[mt][rr] + bzv);
                    float hn = aH[mt][rr] + bhN;
                    float nn = tanh_f(aI[mt][rr] + biN + rv*hn);
                    float h2 = (1.f - zv)*nn + zv*hreg[mt][rr];
                    hreg[mt][rr] = h2;
                    Hs[swz_slot(row, col)] = f2b(h2);
                }
            __syncthreads();
        } else {
            const int bp0 = b*64;
            #pragma unroll
            for (int mt = 0; mt < 4; ++mt)
                #pragma unroll
                for (int rr = 0; rr < 4; ++rr) {
                    const int row = mt*16 + lk8*4 + rr;
                    float rv = sigm_f(aR[mt][rr] + brv);
                    float zv = sigm_f(aZ[mt][rr] + bzv);
                    float hn = aH[mt][rr] + bhN;
                    float nn = tanh_f(aI[mt][rr] + biN + rv*hn);
                    float h2 = (1.f - zv)*nn + zv*hreg[mt][rr];
                    out[(size_t)(bp0 + row)*128 + col] = h2;
                }
        }
    }
}

extern "C" void kernel_launch(void* const* d_in, const int* in_sizes, int n_in,
                              void* d_out, int out_size, void* d_ws, size_t ws_size,
                              hipStream_t stream)
{
    const int*   path   = (const int*)d_in[0];
    const int*   pair   = (const int*)d_in[1];
    const int*   relset = (const int*)d_in[2];
    const float* emb    = (const float*)d_in[3];
    const float* wd     = (const float*)d_in[4];
    const float* bd     = (const float*)d_in[5];
    const float* we     = (const float*)d_in[6];
    const float* be     = (const float*)d_in[7];
    const float* wp     = (const float*)d_in[8];
    const float* bp     = (const float*)d_in[9];
    const float* eu     = (const float*)d_in[10];
    const float* eub    = (const float*)d_in[11];
    const float* wih    = (const float*)d_in[12];
    const float* whh    = (const float*)d_in[13];
    const float* bih    = (const float*)d_in[14];
    const float* bhh    = (const float*)d_in[15];
    float* out = (float*)d_out;
    float* ws  = (float*)d_ws;

    // workspace: only bf16 weights (~288 KB)
    u16* wdb = (u16*)ws;               // 16384 u16
    u16* web = wdb + 16384;
    u16* wpb = web + 16384;
    u16* wib = wpb + 16384;            // 49152 u16
    u16* whb = wib + 49152;            // ends at 147456 u16 = 288 KB

    k_wcvt<<<18, 1024, 0, stream>>>(wd, we, wp, wih, whh, wdb, web, wpb, wib, whb);
    k_mega<<<B_, 512, 0, stream>>>(pair, relset, path, emb, eu, eub,
                                   wdb, bd, web, be, wpb, bp,
                                   wib, whb, bih, bhh, out);
}